// Round 1
// baseline (3296.716 us; speedup 1.0000x reference)
//
#include <hip/hip_runtime.h>

#define GI   768
#define HID  150
#define HPAD 160
#define DDIM 20

// ---------------- segment boundaries: segs[m] = lower_bound(mention_ids, m) ----
__global__ void seg_kernel(const int* __restrict__ mI, int* __restrict__ segs,
                           int P, int S) {
  int m = blockIdx.x * 256 + threadIdx.x;
  if (m > S) return;
  int lo = 0, hi = P;
  while (lo < hi) { int mid = (lo + hi) >> 1; if (mI[mid] < m) lo = mid + 1; else hi = mid; }
  segs[m] = lo;
}

// ---------------- phi lookup tables: phiW[21][HPAD] ---------------------------
// rows 0..9 dist, 10..17 genre, 18..20 speaker.
// phiW[row][h] = sum_k emb[row][k] * W1[(3*GI + block*20 + k)*HID + h]
__global__ void phi_kernel(const float* __restrict__ de, const float* __restrict__ ge,
                           const float* __restrict__ se, const float* __restrict__ W1,
                           float* __restrict__ phiW) {
  int idx = blockIdx.x * 256 + threadIdx.x;
  if (idx >= 21 * HPAD) return;
  int row = idx / HPAD, h = idx % HPAD;
  float v = 0.f;
  if (h < HID) {
    const float* emb; int off;
    if (row < 10)      { emb = de + row * DDIM;        off = 0; }
    else if (row < 18) { emb = ge + (row - 10) * DDIM; off = DDIM; }
    else               { emb = se + (row - 18) * DDIM; off = 2 * DDIM; }
    for (int k = 0; k < DDIM; ++k) v += emb[k] * W1[(3 * GI + off + k) * HID + h];
  }
  phiW[row * HPAD + h] = v;
}

// shared MAC over a 32-deep K chunk: acc[8][4] += q[64][32-chunk] * Wt[32][HPAD]
#define MAC32(QPTR, QSTRIDE)                                                     \
  _Pragma("unroll")                                                              \
  for (int k4 = 0; k4 < 32; k4 += 4) {                                           \
    const float4 w0 = *(const float4*)&Wt[k4 + 0][4 * c];                        \
    const float4 w1 = *(const float4*)&Wt[k4 + 1][4 * c];                        \
    const float4 w2 = *(const float4*)&Wt[k4 + 2][4 * c];                        \
    const float4 w3 = *(const float4*)&Wt[k4 + 3][4 * c];                        \
    _Pragma("unroll")                                                            \
    for (int i = 0; i < 8; ++i) {                                                \
      const float4 q = *(const float4*)((QPTR) + (r * 8 + i) * (QSTRIDE) + k4);  \
      acc[i][0] += q.x * w0.x; acc[i][0] += q.y * w1.x;                          \
      acc[i][0] += q.z * w2.x; acc[i][0] += q.w * w3.x;                          \
      acc[i][1] += q.x * w0.y; acc[i][1] += q.y * w1.y;                          \
      acc[i][1] += q.z * w2.y; acc[i][1] += q.w * w3.y;                          \
      acc[i][2] += q.x * w0.z; acc[i][2] += q.y * w1.z;                          \
      acc[i][2] += q.z * w2.z; acc[i][2] += q.w * w3.z;                          \
      acc[i][3] += q.x * w0.w; acc[i][3] += q.y * w1.w;                          \
      acc[i][3] += q.z * w2.w; acc[i][3] += q.w * w3.w;                          \
    }                                                                            \
  }

// ---------------- pre[s][0:150] = g[s]@W1a, pre[s][150:300] = g[s]@W1b --------
__global__ __launch_bounds__(320) void pre_kernel(const float* __restrict__ g,
                                                  const float* __restrict__ W1,
                                                  float* __restrict__ pre, int S) {
  __shared__ float qt[64][32];
  __shared__ float Wt[32][HPAD];
  const int t = threadIdx.x;
  const int row0 = blockIdx.x * 64;
  const int hbase = blockIdx.y * HPAD;   // 0 or 160; valid h2 < 300
  const int c = t % 40, r = t / 40;
  float acc[8][4];
#pragma unroll
  for (int i = 0; i < 8; ++i) { acc[i][0] = acc[i][1] = acc[i][2] = acc[i][3] = 0.f; }

  for (int d0 = 0; d0 < GI; d0 += 32) {
    __syncthreads();
    for (int idx = t; idx < 64 * 32; idx += 320) {
      int p = idx >> 5, k = idx & 31;
      int s = row0 + p;
      qt[p][k] = (s < S) ? g[s * GI + d0 + k] : 0.f;
    }
    for (int idx = t; idx < 32 * HPAD; idx += 320) {
      int k = idx / HPAD, h = idx % HPAD;
      int h2 = hbase + h;
      float w;
      if (h2 < HID)            w = W1[(d0 + k) * HID + h2];
      else if (h2 < 2 * HID)   w = W1[(GI + d0 + k) * HID + (h2 - HID)];
      else                     w = 0.f;
      Wt[k][h] = w;
    }
    __syncthreads();
    MAC32(&qt[0][0], 32)
  }
#pragma unroll
  for (int i = 0; i < 8; ++i) {
    int s = row0 + r * 8 + i;
    if (s >= S) continue;
#pragma unroll
    for (int u = 0; u < 4; ++u) {
      int h2 = hbase + 4 * c + u;
      if (h2 < 2 * HID) pre[s * (2 * HID) + h2] = acc[i][u];
    }
  }
}

// ---------------- fused per-pair MLP: h1 -> h2 -> score -----------------------
__global__ __launch_bounds__(320) void score_kernel(
    const float* __restrict__ g, const float* __restrict__ pre,
    const float* __restrict__ phiW, const float* __restrict__ W1,
    const float* __restrict__ b1, const float* __restrict__ W2,
    const float* __restrict__ b2, const float* __restrict__ W3,
    const float* __restrict__ b3,
    const int* __restrict__ mI, const int* __restrict__ aI,
    const int* __restrict__ db, const int* __restrict__ ge, const int* __restrict__ sp,
    float* __restrict__ sOut, int P) {
  __shared__ float qt[64][32];
  __shared__ float Wt[32][HPAD];
  __shared__ float h1s[64][HPAD];
  __shared__ int sIi[64], sIj[64], sDb[64], sGe[64], sSp[64];
  __shared__ float scoreAcc[64];

  const int t = threadIdx.x;
  const int p0 = blockIdx.x * 64;
  const int c = t % 40, r = t / 40;

  if (t < 64) {
    int p = p0 + t;
    int ok = p < P;
    sIi[t] = ok ? mI[p] : 0; sIj[t] = ok ? aI[p] : 0;
    sDb[t] = ok ? db[p] : 0; sGe[t] = ok ? ge[p] : 0; sSp[t] = ok ? sp[p] : 0;
    scoreAcc[t] = 0.f;
  }
  float acc[8][4];
#pragma unroll
  for (int i = 0; i < 8; ++i) { acc[i][0] = acc[i][1] = acc[i][2] = acc[i][3] = 0.f; }
  __syncthreads();

  // phase 1: acc = (g_i .* g_j) @ W1c  (W1 rows 2*GI .. 3*GI-1)
  for (int d0 = 0; d0 < GI; d0 += 32) {
    for (int idx = t; idx < 64 * 32; idx += 320) {
      int p = idx >> 5, k = idx & 31;
      float a = g[sIi[p] * GI + d0 + k];
      float b = g[sIj[p] * GI + d0 + k];
      qt[p][k] = a * b;
    }
    for (int idx = t; idx < 32 * HPAD; idx += 320) {
      int k = idx / HPAD, h = idx % HPAD;
      Wt[k][h] = (h < HID) ? W1[(2 * GI + d0 + k) * HID + h] : 0.f;
    }
    __syncthreads();
    MAC32(&qt[0][0], 32)
    __syncthreads();
  }

  // h1 epilogue: add per-mention pre, phi tables, bias; relu; stash in LDS
#pragma unroll
  for (int i = 0; i < 8; ++i) {
    int p = r * 8 + i;
    int gi = sIi[p], gj = sIj[p];
    int rd = sDb[p], rg = 10 + sGe[p], rs = 18 + sSp[p];
#pragma unroll
    for (int u = 0; u < 4; ++u) {
      int h = 4 * c + u;
      float v = 0.f;
      if (h < HID) {
        v = acc[i][u] + b1[h]
          + pre[gi * (2 * HID) + h] + pre[gj * (2 * HID) + HID + h]
          + phiW[rd * HPAD + h] + phiW[rg * HPAD + h] + phiW[rs * HPAD + h];
        v = fmaxf(v, 0.f);
      }
      h1s[p][h] = v;
    }
  }
  __syncthreads();

  // phase 2: h2 = relu(h1 @ W2 + b2), score = h2 @ W3 + b3
#pragma unroll
  for (int i = 0; i < 8; ++i) { acc[i][0] = acc[i][1] = acc[i][2] = acc[i][3] = 0.f; }
  for (int k0 = 0; k0 < HPAD; k0 += 32) {
    for (int idx = t; idx < 32 * HPAD; idx += 320) {
      int k = idx / HPAD, h = idx % HPAD;
      int kg = k0 + k;
      Wt[k][h] = (kg < HID && h < HID) ? W2[kg * HID + h] : 0.f;
    }
    __syncthreads();
    MAC32(&h1s[0][0] + k0, HPAD)
    __syncthreads();
  }
#pragma unroll
  for (int i = 0; i < 8; ++i) {
    int p = r * 8 + i;
    float partial = 0.f;
#pragma unroll
    for (int u = 0; u < 4; ++u) {
      int h = 4 * c + u;
      if (h < HID) {
        float h2v = fmaxf(acc[i][u] + b2[h], 0.f);
        partial += h2v * W3[h];
      }
    }
    atomicAdd(&scoreAcc[p], partial);
  }
  __syncthreads();
  if (t < 64 && p0 + t < P) sOut[p0 + t] = scoreAcc[t] + b3[0];
}

// ---------------- mid: segment softmax -> weighted -> gated g update ----------
__global__ void mid_kernel(const float* __restrict__ g, const float* __restrict__ s1,
                           const int* __restrict__ segs, const int* __restrict__ aI,
                           const float* __restrict__ Wf, const float* __restrict__ bf,
                           float* __restrict__ g2) {
  const int m = blockIdx.x;
  const int t = threadIdx.x;  // 256
  const int st = segs[m], en = segs[m + 1], n = en - st;
  if (n == 0) {  // counts == 0: keep g
    for (int d = t; d < GI; d += 256) g2[m * GI + d] = g[m * GI + d];
    return;
  }
  __shared__ float red[256];
  // segment max
  float mx = -INFINITY;
  for (int p = st + t; p < en; p += 256) mx = fmaxf(mx, s1[p]);
  red[t] = mx; __syncthreads();
  for (int s = 128; s > 0; s >>= 1) { if (t < s) red[t] = fmaxf(red[t], red[t + s]); __syncthreads(); }
  mx = red[0]; __syncthreads();
  // denom
  float sm = 0.f;
  for (int p = st + t; p < en; p += 256) sm += expf(s1[p] - mx);
  red[t] = sm; __syncthreads();
  for (int s = 128; s > 0; s >>= 1) { if (t < s) red[t] += red[t + s]; __syncthreads(); }
  const float denom = red[0]; __syncthreads();
  // weighted = sum_p e_p * g[j_p] / denom ; each thread owns 3 d-slots
  float w[3] = {0.f, 0.f, 0.f};
  for (int p = st; p < en; ++p) {
    float e = expf(s1[p] - mx);
    const float* gj = g + aI[p] * GI;
#pragma unroll
    for (int u = 0; u < 3; ++u) w[u] += e * gj[t + u * 256];
  }
#pragma unroll
  for (int u = 0; u < 3; ++u) w[u] /= denom;
  // f = sigmoid([g_m, weighted] @ Wf + bf)
  float part = 0.f;
#pragma unroll
  for (int u = 0; u < 3; ++u) {
    int d = t + u * 256;
    part += g[m * GI + d] * Wf[d] + w[u] * Wf[GI + d];
  }
  red[t] = part; __syncthreads();
  for (int s = 128; s > 0; s >>= 1) { if (t < s) red[t] += red[t + s]; __syncthreads(); }
  const float f = 1.f / (1.f + expf(-(red[0] + bf[0])));
#pragma unroll
  for (int u = 0; u < 3; ++u) {
    int d = t + u * 256;
    g2[m * GI + d] = f * (float)m + (1.f - f) * w[u];
  }
}

// ---------------- coref_scores[p] = ms[i] + ms[j] + s2[p] ---------------------
__global__ void coref_kernel(const float* __restrict__ ms, const float* __restrict__ s2,
                             const int* __restrict__ mI, const int* __restrict__ aI,
                             float* __restrict__ out, int P) {
  int p = blockIdx.x * 256 + threadIdx.x;
  if (p >= P) return;
  out[p] = ms[mI[p]] + ms[aI[p]] + s2[p];
}

// ---------------- final segment softmax with epsilon --------------------------
__global__ void final_kernel(const float* __restrict__ c, const int* __restrict__ segs,
                             float* __restrict__ pairP, float* __restrict__ epsP) {
  const int m = blockIdx.x;
  const int t = threadIdx.x;  // 256
  const int st = segs[m], en = segs[m + 1], n = en - st;
  __shared__ float red[256];
  float mx = -INFINITY;
  for (int p = st + t; p < en; p += 256) mx = fmaxf(mx, c[p]);
  red[t] = mx; __syncthreads();
  for (int s = 128; s > 0; s >>= 1) { if (t < s) red[t] = fmaxf(red[t], red[t + s]); __syncthreads(); }
  mx = red[0]; __syncthreads();
  const float m2 = (n > 0) ? fmaxf(mx, 0.f) : 0.f;
  float sm = 0.f;
  for (int p = st + t; p < en; p += 256) sm += expf(c[p] - m2);
  red[t] = sm; __syncthreads();
  for (int s = 128; s > 0; s >>= 1) { if (t < s) red[t] += red[t + s]; __syncthreads(); }
  const float denom = red[0] + expf(-m2);
  for (int p = st + t; p < en; p += 256) pairP[p] = expf(c[p] - m2) / denom;
  if (t == 0) epsP[m] = expf(-m2) / denom;
}

extern "C" void kernel_launch(void* const* d_in, const int* in_sizes, int n_in,
                              void* d_out, int out_size, void* d_ws, size_t ws_size,
                              hipStream_t stream) {
  const float* g_i  = (const float*)d_in[0];
  const float* ms   = (const float*)d_in[1];
  const int*   mI   = (const int*)d_in[2];
  const int*   aI   = (const int*)d_in[3];
  const int*   db   = (const int*)d_in[4];
  const int*   ge   = (const int*)d_in[5];
  const int*   sp   = (const int*)d_in[6];
  const float* de   = (const float*)d_in[7];
  const float* gemb = (const float*)d_in[8];
  const float* semb = (const float*)d_in[9];
  const float* W1   = (const float*)d_in[10];
  const float* b1   = (const float*)d_in[11];
  const float* W2   = (const float*)d_in[12];
  const float* b2   = (const float*)d_in[13];
  const float* W3   = (const float*)d_in[14];
  const float* b3   = (const float*)d_in[15];
  const float* Wf   = (const float*)d_in[16];
  const float* bf   = (const float*)d_in[17];

  const int S = in_sizes[0] / GI;
  const int P = in_sizes[2];
  float* out = (float*)d_out;                 // [coref P | pairP P | epsP S]

  char* ws = (char*)d_ws;
  size_t off = 0;
  auto take = [&](size_t bytes) -> char* {
    char* p = ws + off;
    off = (off + bytes + 15) & ~(size_t)15;
    return p;
  };
  int*   segs = (int*)  take((size_t)(S + 1) * 4);
  float* phiW = (float*)take((size_t)21 * HPAD * 4);
  float* pre  = (float*)take((size_t)S * 2 * HID * 4);
  float* g2   = (float*)take((size_t)S * GI * 4);
  float* s1   = (float*)take((size_t)P * 4);
  float* s2   = (float*)take((size_t)P * 4);

  const int gridSeg  = (S + 1 + 255) / 256;
  const int gridPhi  = (21 * HPAD + 255) / 256;
  const dim3 gridPre((S + 63) / 64, 2);
  const int gridScr  = (P + 63) / 64;
  const int gridCor  = (P + 255) / 256;

  seg_kernel<<<gridSeg, 256, 0, stream>>>(mI, segs, P, S);
  phi_kernel<<<gridPhi, 256, 0, stream>>>(de, gemb, semb, W1, phiW);

  // iteration 1 (g = g_i)
  pre_kernel<<<gridPre, 320, 0, stream>>>(g_i, W1, pre, S);
  score_kernel<<<gridScr, 320, 0, stream>>>(g_i, pre, phiW, W1, b1, W2, b2, W3, b3,
                                            mI, aI, db, ge, sp, s1, P);
  mid_kernel<<<S, 256, 0, stream>>>(g_i, s1, segs, aI, Wf, bf, g2);

  // iteration 2 (g = g2)
  pre_kernel<<<gridPre, 320, 0, stream>>>(g2, W1, pre, S);
  score_kernel<<<gridScr, 320, 0, stream>>>(g2, pre, phiW, W1, b1, W2, b2, W3, b3,
                                            mI, aI, db, ge, sp, s2, P);

  // outputs
  coref_kernel<<<gridCor, 256, 0, stream>>>(ms, s2, mI, aI, out, P);
  final_kernel<<<S, 256, 0, stream>>>(out, segs, out + P, out + 2 * (size_t)P);
}

// Round 2
// 1936.391 us; speedup vs baseline: 1.7025x; 1.7025x over previous
//
#include <hip/hip_runtime.h>

#define GI   768
#define HID  150
#define HPAD 160
#define DDIM 20

// ---------------- segment boundaries: segs[m] = lower_bound(mention_ids, m) ----
__global__ void seg_kernel(const int* __restrict__ mI, int* __restrict__ segs,
                           int P, int S) {
  int m = blockIdx.x * 256 + threadIdx.x;
  if (m > S) return;
  int lo = 0, hi = P;
  while (lo < hi) { int mid = (lo + hi) >> 1; if (mI[mid] < m) lo = mid + 1; else hi = mid; }
  segs[m] = lo;
}

// ---------------- phi lookup tables: phiW[21][HPAD] ---------------------------
__global__ void phi_kernel(const float* __restrict__ de, const float* __restrict__ ge,
                           const float* __restrict__ se, const float* __restrict__ W1,
                           float* __restrict__ phiW) {
  int idx = blockIdx.x * 256 + threadIdx.x;
  if (idx >= 21 * HPAD) return;
  int row = idx / HPAD, h = idx % HPAD;
  float v = 0.f;
  if (h < HID) {
    const float* emb; int off;
    if (row < 10)      { emb = de + row * DDIM;        off = 0; }
    else if (row < 18) { emb = ge + (row - 10) * DDIM; off = DDIM; }
    else               { emb = se + (row - 18) * DDIM; off = 2 * DDIM; }
    for (int k = 0; k < DDIM; ++k) v += emb[k] * W1[(3 * GI + off + k) * HID + h];
  }
  phiW[row * HPAD + h] = v;
}

// MAC over a 32-deep K chunk: acc[4][4] += q[32 rows][k-chunk] * Wt[32][HPAD]
// thread -> (c = t%40 : h-chunk, r = t/40 : 4-row group)
#define MAC4(QPTR, QSTRIDE)                                                      \
  _Pragma("unroll")                                                              \
  for (int k4 = 0; k4 < 32; k4 += 4) {                                           \
    const float4 w0 = *(const float4*)&Wt[k4 + 0][4 * c];                        \
    const float4 w1 = *(const float4*)&Wt[k4 + 1][4 * c];                        \
    const float4 w2 = *(const float4*)&Wt[k4 + 2][4 * c];                        \
    const float4 w3 = *(const float4*)&Wt[k4 + 3][4 * c];                        \
    _Pragma("unroll")                                                            \
    for (int i = 0; i < 4; ++i) {                                                \
      const float4 q = *(const float4*)((QPTR) + (r * 4 + i) * (QSTRIDE) + k4);  \
      acc[i][0] += q.x * w0.x; acc[i][0] += q.y * w1.x;                          \
      acc[i][0] += q.z * w2.x; acc[i][0] += q.w * w3.x;                          \
      acc[i][1] += q.x * w0.y; acc[i][1] += q.y * w1.y;                          \
      acc[i][1] += q.z * w2.y; acc[i][1] += q.w * w3.y;                          \
      acc[i][2] += q.x * w0.z; acc[i][2] += q.y * w1.z;                          \
      acc[i][2] += q.z * w2.z; acc[i][2] += q.w * w3.z;                          \
      acc[i][3] += q.x * w0.w; acc[i][3] += q.y * w1.w;                          \
      acc[i][3] += q.z * w2.w; acc[i][3] += q.w * w3.w;                          \
    }                                                                            \
  }

// ---------------- pre[s][0:150] = g[s]@W1a, pre[s][150:300] = g[s]@W1b --------
__global__ __launch_bounds__(320, 8) void pre_kernel(const float* __restrict__ g,
                                                     const float* __restrict__ W1,
                                                     float* __restrict__ pre, int S) {
  __shared__ float qt[32][32];
  __shared__ float Wt[32][HPAD];
  const int t = threadIdx.x;
  const int row0 = blockIdx.x * 32;
  const int hbase = blockIdx.y * HPAD;   // 0 or 160; valid h2 < 300
  const int c = t % 40, r = t / 40;
  float acc[4][4];
#pragma unroll
  for (int i = 0; i < 4; ++i) { acc[i][0] = acc[i][1] = acc[i][2] = acc[i][3] = 0.f; }

  for (int d0 = 0; d0 < GI; d0 += 32) {
    __syncthreads();
    for (int idx = t; idx < 32 * 32; idx += 320) {
      int p = idx >> 5, k = idx & 31;
      int s = row0 + p;
      qt[p][k] = (s < S) ? g[s * GI + d0 + k] : 0.f;
    }
    for (int idx = t; idx < 32 * HPAD; idx += 320) {
      int k = idx / HPAD, h = idx % HPAD;
      int h2 = hbase + h;
      float w;
      if (h2 < HID)            w = W1[(d0 + k) * HID + h2];
      else if (h2 < 2 * HID)   w = W1[(GI + d0 + k) * HID + (h2 - HID)];
      else                     w = 0.f;
      Wt[k][h] = w;
    }
    __syncthreads();
    MAC4(&qt[0][0], 32)
  }
#pragma unroll
  for (int i = 0; i < 4; ++i) {
    int s = row0 + r * 4 + i;
    if (s >= S) continue;
#pragma unroll
    for (int u = 0; u < 4; ++u) {
      int h2 = hbase + 4 * c + u;
      if (h2 < 2 * HID) pre[s * (2 * HID) + h2] = acc[i][u];
    }
  }
}

// ---------------- h1 GEMM: h1[p][h] = relu((g_i.*g_j)@W1c + pre_i + pre_j + phi + b1)
__global__ __launch_bounds__(320, 8) void h1_kernel(
    const float* __restrict__ g, const float* __restrict__ pre,
    const float* __restrict__ phiW, const float* __restrict__ W1,
    const float* __restrict__ b1,
    const int* __restrict__ mI, const int* __restrict__ aI,
    const int* __restrict__ db, const int* __restrict__ ge, const int* __restrict__ sp,
    float* __restrict__ h1buf, int P) {
  __shared__ float qt[32][32];
  __shared__ float Wt[32][HPAD];
  __shared__ int sIi[32], sIj[32], sDb[32], sGe[32], sSp[32];

  const int t = threadIdx.x;
  const int p0 = blockIdx.x * 32;
  const int c = t % 40, r = t / 40;

  if (t < 32) {
    int p = p0 + t;
    sIi[t] = mI[p]; sIj[t] = aI[p];
    sDb[t] = db[p]; sGe[t] = ge[p]; sSp[t] = sp[p];
  }
  float acc[4][4];
#pragma unroll
  for (int i = 0; i < 4; ++i) { acc[i][0] = acc[i][1] = acc[i][2] = acc[i][3] = 0.f; }
  __syncthreads();

  for (int d0 = 0; d0 < GI; d0 += 32) {
    for (int idx = t; idx < 32 * 32; idx += 320) {
      int p = idx >> 5, k = idx & 31;
      float a = g[sIi[p] * GI + d0 + k];
      float b = g[sIj[p] * GI + d0 + k];
      qt[p][k] = a * b;
    }
    for (int idx = t; idx < 32 * HPAD; idx += 320) {
      int k = idx / HPAD, h = idx % HPAD;
      Wt[k][h] = (h < HID) ? W1[(2 * GI + d0 + k) * HID + h] : 0.f;
    }
    __syncthreads();
    MAC4(&qt[0][0], 32)
    __syncthreads();
  }

  // epilogue: add per-mention pre, phi tables, bias; relu; write h1 row chunk
#pragma unroll
  for (int i = 0; i < 4; ++i) {
    int p = r * 4 + i;
    int gi = sIi[p], gj = sIj[p];
    int rd = sDb[p], rg = 10 + sGe[p], rs = 18 + sSp[p];
    float4 o;
    float* ov = (float*)&o;
#pragma unroll
    for (int u = 0; u < 4; ++u) {
      int h = 4 * c + u;
      float v = 0.f;
      if (h < HID) {
        v = acc[i][u] + b1[h]
          + pre[gi * (2 * HID) + h] + pre[gj * (2 * HID) + HID + h]
          + phiW[rd * HPAD + h] + phiW[rg * HPAD + h] + phiW[rs * HPAD + h];
        v = fmaxf(v, 0.f);
      }
      ov[u] = v;
    }
    *(float4*)&h1buf[(size_t)(p0 + p) * HPAD + 4 * c] = o;
  }
}

// ---------------- score GEMM: score[p] = relu(h1@W2 + b2) @ W3 + b3 ----------
__global__ __launch_bounds__(320, 8) void score2_kernel(
    const float* __restrict__ h1buf, const float* __restrict__ W2,
    const float* __restrict__ b2, const float* __restrict__ W3,
    const float* __restrict__ b3, float* __restrict__ sOut, int P) {
  __shared__ float qt[32][32];
  __shared__ float Wt[32][HPAD];
  __shared__ float scoreAcc[32];

  const int t = threadIdx.x;
  const int p0 = blockIdx.x * 32;
  const int c = t % 40, r = t / 40;

  if (t < 32) scoreAcc[t] = 0.f;
  float acc[4][4];
#pragma unroll
  for (int i = 0; i < 4; ++i) { acc[i][0] = acc[i][1] = acc[i][2] = acc[i][3] = 0.f; }

  for (int k0 = 0; k0 < HPAD; k0 += 32) {
    __syncthreads();
    for (int idx = t; idx < 32 * 32; idx += 320) {
      int p = idx >> 5, k = idx & 31;
      qt[p][k] = h1buf[(size_t)(p0 + p) * HPAD + k0 + k];
    }
    for (int idx = t; idx < 32 * HPAD; idx += 320) {
      int k = idx / HPAD, h = idx % HPAD;
      int kg = k0 + k;
      Wt[k][h] = (kg < HID && h < HID) ? W2[kg * HID + h] : 0.f;
    }
    __syncthreads();
    MAC4(&qt[0][0], 32)
  }
  __syncthreads();
#pragma unroll
  for (int i = 0; i < 4; ++i) {
    int p = r * 4 + i;
    float partial = 0.f;
#pragma unroll
    for (int u = 0; u < 4; ++u) {
      int h = 4 * c + u;
      if (h < HID) {
        float h2v = fmaxf(acc[i][u] + b2[h], 0.f);
        partial += h2v * W3[h];
      }
    }
    atomicAdd(&scoreAcc[p], partial);
  }
  __syncthreads();
  if (t < 32) sOut[p0 + t] = scoreAcc[t] + b3[0];
}

// ---------------- mid: segment softmax -> weighted -> gated g update ----------
__global__ void mid_kernel(const float* __restrict__ g, const float* __restrict__ s1,
                           const int* __restrict__ segs, const int* __restrict__ aI,
                           const float* __restrict__ Wf, const float* __restrict__ bf,
                           float* __restrict__ g2) {
  const int m = blockIdx.x;
  const int t = threadIdx.x;  // 256
  const int st = segs[m], en = segs[m + 1], n = en - st;
  if (n == 0) {
    for (int d = t; d < GI; d += 256) g2[m * GI + d] = g[m * GI + d];
    return;
  }
  __shared__ float red[256];
  float mx = -INFINITY;
  for (int p = st + t; p < en; p += 256) mx = fmaxf(mx, s1[p]);
  red[t] = mx; __syncthreads();
  for (int s = 128; s > 0; s >>= 1) { if (t < s) red[t] = fmaxf(red[t], red[t + s]); __syncthreads(); }
  mx = red[0]; __syncthreads();
  float sm = 0.f;
  for (int p = st + t; p < en; p += 256) sm += expf(s1[p] - mx);
  red[t] = sm; __syncthreads();
  for (int s = 128; s > 0; s >>= 1) { if (t < s) red[t] += red[t + s]; __syncthreads(); }
  const float denom = red[0]; __syncthreads();
  float w[3] = {0.f, 0.f, 0.f};
  for (int p = st; p < en; ++p) {
    float e = expf(s1[p] - mx);
    const float* gj = g + aI[p] * GI;
#pragma unroll
    for (int u = 0; u < 3; ++u) w[u] += e * gj[t + u * 256];
  }
#pragma unroll
  for (int u = 0; u < 3; ++u) w[u] /= denom;
  float part = 0.f;
#pragma unroll
  for (int u = 0; u < 3; ++u) {
    int d = t + u * 256;
    part += g[m * GI + d] * Wf[d] + w[u] * Wf[GI + d];
  }
  red[t] = part; __syncthreads();
  for (int s = 128; s > 0; s >>= 1) { if (t < s) red[t] += red[t + s]; __syncthreads(); }
  const float f = 1.f / (1.f + expf(-(red[0] + bf[0])));
#pragma unroll
  for (int u = 0; u < 3; ++u) {
    int d = t + u * 256;
    g2[m * GI + d] = f * (float)m + (1.f - f) * w[u];
  }
}

// ---------------- coref_scores[p] = ms[i] + ms[j] + s2[p] ---------------------
__global__ void coref_kernel(const float* __restrict__ ms, const float* __restrict__ s2,
                             const int* __restrict__ mI, const int* __restrict__ aI,
                             float* __restrict__ out, int P) {
  int p = blockIdx.x * 256 + threadIdx.x;
  if (p >= P) return;
  out[p] = ms[mI[p]] + ms[aI[p]] + s2[p];
}

// ---------------- final segment softmax with epsilon --------------------------
__global__ void final_kernel(const float* __restrict__ c, const int* __restrict__ segs,
                             float* __restrict__ pairP, float* __restrict__ epsP) {
  const int m = blockIdx.x;
  const int t = threadIdx.x;  // 256
  const int st = segs[m], en = segs[m + 1], n = en - st;
  __shared__ float red[256];
  float mx = -INFINITY;
  for (int p = st + t; p < en; p += 256) mx = fmaxf(mx, c[p]);
  red[t] = mx; __syncthreads();
  for (int s = 128; s > 0; s >>= 1) { if (t < s) red[t] = fmaxf(red[t], red[t + s]); __syncthreads(); }
  mx = red[0]; __syncthreads();
  const float m2 = (n > 0) ? fmaxf(mx, 0.f) : 0.f;
  float sm = 0.f;
  for (int p = st + t; p < en; p += 256) sm += expf(c[p] - m2);
  red[t] = sm; __syncthreads();
  for (int s = 128; s > 0; s >>= 1) { if (t < s) red[t] += red[t + s]; __syncthreads(); }
  const float denom = red[0] + expf(-m2);
  for (int p = st + t; p < en; p += 256) pairP[p] = expf(c[p] - m2) / denom;
  if (t == 0) epsP[m] = expf(-m2) / denom;
}

extern "C" void kernel_launch(void* const* d_in, const int* in_sizes, int n_in,
                              void* d_out, int out_size, void* d_ws, size_t ws_size,
                              hipStream_t stream) {
  const float* g_i  = (const float*)d_in[0];
  const float* ms   = (const float*)d_in[1];
  const int*   mI   = (const int*)d_in[2];
  const int*   aI   = (const int*)d_in[3];
  const int*   db   = (const int*)d_in[4];
  const int*   ge   = (const int*)d_in[5];
  const int*   sp   = (const int*)d_in[6];
  const float* de   = (const float*)d_in[7];
  const float* gemb = (const float*)d_in[8];
  const float* semb = (const float*)d_in[9];
  const float* W1   = (const float*)d_in[10];
  const float* b1   = (const float*)d_in[11];
  const float* W2   = (const float*)d_in[12];
  const float* b2   = (const float*)d_in[13];
  const float* W3   = (const float*)d_in[14];
  const float* b3   = (const float*)d_in[15];
  const float* Wf   = (const float*)d_in[16];
  const float* bf   = (const float*)d_in[17];

  const int S = in_sizes[0] / GI;
  const int P = in_sizes[2];
  float* out = (float*)d_out;                 // [coref P | pairP P | epsP S]

  char* ws = (char*)d_ws;
  size_t off = 0;
  auto take = [&](size_t bytes) -> char* {
    char* p = ws + off;
    off = (off + bytes + 15) & ~(size_t)15;
    return p;
  };
  int*   segs = (int*)  take((size_t)(S + 1) * 4);
  float* phiW = (float*)take((size_t)21 * HPAD * 4);
  float* pre  = (float*)take((size_t)S * 2 * HID * 4);
  float* g2   = (float*)take((size_t)S * GI * 4);
  float* s1   = (float*)take((size_t)P * 4);
  float* s2   = (float*)take((size_t)P * 4);
  float* h1b  = (float*)take((size_t)P * HPAD * 4);

  const int gridSeg  = (S + 1 + 255) / 256;
  const int gridPhi  = (21 * HPAD + 255) / 256;
  const dim3 gridPre((S + 31) / 32, 2);
  const int gridScr  = (P + 31) / 32;   // P % 32 == 0
  const int gridCor  = (P + 255) / 256;

  seg_kernel<<<gridSeg, 256, 0, stream>>>(mI, segs, P, S);
  phi_kernel<<<gridPhi, 256, 0, stream>>>(de, gemb, semb, W1, phiW);

  // iteration 1 (g = g_i)
  pre_kernel<<<gridPre, 320, 0, stream>>>(g_i, W1, pre, S);
  h1_kernel<<<gridScr, 320, 0, stream>>>(g_i, pre, phiW, W1, b1,
                                         mI, aI, db, ge, sp, h1b, P);
  score2_kernel<<<gridScr, 320, 0, stream>>>(h1b, W2, b2, W3, b3, s1, P);
  mid_kernel<<<S, 256, 0, stream>>>(g_i, s1, segs, aI, Wf, bf, g2);

  // iteration 2 (g = g2)
  pre_kernel<<<gridPre, 320, 0, stream>>>(g2, W1, pre, S);
  h1_kernel<<<gridScr, 320, 0, stream>>>(g2, pre, phiW, W1, b1,
                                         mI, aI, db, ge, sp, h1b, P);
  score2_kernel<<<gridScr, 320, 0, stream>>>(h1b, W2, b2, W3, b3, s2, P);

  // outputs
  coref_kernel<<<gridCor, 256, 0, stream>>>(ms, s2, mI, aI, out, P);
  final_kernel<<<S, 256, 0, stream>>>(out, segs, out + P, out + 2 * (size_t)P);
}

// Round 3
// 1159.494 us; speedup vs baseline: 2.8432x; 1.6700x over previous
//
#include <hip/hip_runtime.h>

#define GI   768
#define HID  150
#define HPAD 160
#define DDIM 20
#define WPC  480   // padded W1 layout: [A 0..159 | B 160..319 | C 320..479]

// ---------------- segment boundaries: segs[m] = lower_bound(mention_ids, m) ----
__global__ void seg_kernel(const int* __restrict__ mI, int* __restrict__ segs,
                           int P, int S) {
  int m = blockIdx.x * 256 + threadIdx.x;
  if (m > S) return;
  int lo = 0, hi = P;
  while (lo < hi) { int mid = (lo + hi) >> 1; if (mI[mid] < m) lo = mid + 1; else hi = mid; }
  segs[m] = lo;
}

// ---------------- phi lookup tables: phiW[21][HPAD] ---------------------------
__global__ void phi_kernel(const float* __restrict__ de, const float* __restrict__ ge,
                           const float* __restrict__ se, const float* __restrict__ W1,
                           float* __restrict__ phiW) {
  int idx = blockIdx.x * 256 + threadIdx.x;
  if (idx >= 21 * HPAD) return;
  int row = idx / HPAD, h = idx % HPAD;
  float v = 0.f;
  if (h < HID) {
    const float* emb; int off;
    if (row < 10)      { emb = de + row * DDIM;        off = 0; }
    else if (row < 18) { emb = ge + (row - 10) * DDIM; off = DDIM; }
    else               { emb = se + (row - 18) * DDIM; off = 2 * DDIM; }
    for (int k = 0; k < DDIM; ++k) v += emb[k] * W1[(3 * GI + off + k) * HID + h];
  }
  phiW[row * HPAD + h] = v;
}

// ---------------- pad weights into float4-friendly layouts --------------------
__global__ void pad_kernel(const float* __restrict__ W1, const float* __restrict__ W2,
                           const float* __restrict__ b1, const float* __restrict__ b2,
                           const float* __restrict__ W3,
                           float* __restrict__ Wp, float* __restrict__ W2p,
                           float* __restrict__ b1p, float* __restrict__ b2p,
                           float* __restrict__ W3p) {
  int idx = blockIdx.x * 256 + threadIdx.x;
  const int NW = GI * WPC;
  if (idx < NW) {
    int row = idx / WPC, col = idx % WPC;
    int seg = col / HPAD, h = col % HPAD;
    Wp[idx] = (h < HID) ? W1[(seg * GI + row) * HID + h] : 0.f;
    return;
  }
  idx -= NW;
  if (idx < HPAD * HPAD) {
    int row = idx / HPAD, h = idx % HPAD;
    W2p[idx] = (row < HID && h < HID) ? W2[row * HID + h] : 0.f;
    return;
  }
  idx -= HPAD * HPAD;
  if (idx < HPAD) { b1p[idx] = (idx < HID) ? b1[idx] : 0.f; return; }
  idx -= HPAD;
  if (idx < HPAD) { b2p[idx] = (idx < HID) ? b2[idx] : 0.f; return; }
  idx -= HPAD;
  if (idx < HPAD) { W3p[idx] = (idx < HID) ? W3[idx] : 0.f; return; }
}

// MAC over a 32-deep K chunk: acc[8][4] += q[64 rows][chunk] * Wt[32][HPAD]
// thread -> (c = t%40 : 4-wide h-chunk, r = t/40 : 8-row group)
#define MAC8(QPTR, QSTRIDE)                                                      \
  _Pragma("unroll")                                                              \
  for (int k4 = 0; k4 < 32; k4 += 4) {                                           \
    const float4 w0 = *(const float4*)&Wt[k4 + 0][4 * c];                        \
    const float4 w1 = *(const float4*)&Wt[k4 + 1][4 * c];                        \
    const float4 w2 = *(const float4*)&Wt[k4 + 2][4 * c];                        \
    const float4 w3 = *(const float4*)&Wt[k4 + 3][4 * c];                        \
    _Pragma("unroll")                                                            \
    for (int i = 0; i < 8; ++i) {                                                \
      const float4 q = *(const float4*)((QPTR) + (r * 8 + i) * (QSTRIDE) + k4);  \
      acc[i][0] += q.x * w0.x; acc[i][0] += q.y * w1.x;                          \
      acc[i][0] += q.z * w2.x; acc[i][0] += q.w * w3.x;                          \
      acc[i][1] += q.x * w0.y; acc[i][1] += q.y * w1.y;                          \
      acc[i][1] += q.z * w2.y; acc[i][1] += q.w * w3.y;                          \
      acc[i][2] += q.x * w0.z; acc[i][2] += q.y * w1.z;                          \
      acc[i][2] += q.z * w2.z; acc[i][2] += q.w * w3.z;                          \
      acc[i][3] += q.x * w0.w; acc[i][3] += q.y * w1.w;                          \
      acc[i][3] += q.z * w2.w; acc[i][3] += q.w * w3.w;                          \
    }                                                                            \
  }

// ---------------- pre[s][0:160] = g[s]@W1a, pre[s][160:320] = g[s]@W1b --------
__global__ __launch_bounds__(320, 5) void pre_kernel(const float* __restrict__ g,
                                                     const float* __restrict__ Wp,
                                                     float* __restrict__ pre, int S) {
  __shared__ float qt[64][32];
  __shared__ float Wt[32][HPAD];
  const int t = threadIdx.x;
  const int row0 = blockIdx.x * 64;
  const int hbase = blockIdx.y * HPAD;   // 0 -> A, 160 -> B
  const int c = t % 40, r = t / 40;
  float acc[8][4];
#pragma unroll
  for (int i = 0; i < 8; ++i) { acc[i][0] = acc[i][1] = acc[i][2] = acc[i][3] = 0.f; }

  // hoisted staging pointers
  const int rowA = t >> 3, q4A = t & 7;
  const int rowB = (t + 320) >> 3, q4B = (t + 320) & 7;
  const bool okA = (row0 + rowA) < S;
  const bool okB = (t < 192) && ((row0 + rowB) < S);
  const float* gA = g + (size_t)(row0 + rowA) * GI + 4 * q4A;
  const float* gB = g + (size_t)(row0 + rowB) * GI + 4 * q4B;
  float* qdA = &qt[rowA][4 * q4A];
  float* qdB = &qt[rowB][4 * q4B];
  if (!okA) *(float4*)qdA = make_float4(0.f, 0.f, 0.f, 0.f);
  if (t < 192 && !okB) *(float4*)qdB = make_float4(0.f, 0.f, 0.f, 0.f);
  int wrow[4], wc4[4];
  const float* wsrc[4]; float* wdst[4];
#pragma unroll
  for (int rep = 0; rep < 4; ++rep) {
    int idx = rep * 320 + t;
    wrow[rep] = idx / 40; wc4[rep] = idx % 40;
    wsrc[rep] = Wp + (size_t)wrow[rep] * WPC + hbase + 4 * wc4[rep];
    wdst[rep] = &Wt[wrow[rep]][4 * wc4[rep]];
  }

#pragma unroll 1
  for (int d0 = 0; d0 < GI; d0 += 32) {
    __syncthreads();
    if (okA) *(float4*)qdA = *(const float4*)(gA + d0);
    if (okB) *(float4*)qdB = *(const float4*)(gB + d0);
#pragma unroll
    for (int rep = 0; rep < 4; ++rep)
      *(float4*)wdst[rep] = *(const float4*)(wsrc[rep] + (size_t)d0 * WPC);
    __syncthreads();
    MAC8(&qt[0][0], 32)
  }
#pragma unroll
  for (int i = 0; i < 8; ++i) {
    int s = row0 + r * 8 + i;
    if (s < S) {
      float4 o = make_float4(acc[i][0], acc[i][1], acc[i][2], acc[i][3]);
      *(float4*)&pre[(size_t)s * (2 * HPAD) + hbase + 4 * c] = o;
    }
  }
}

// ---------------- h1[p][h] = relu((g_i.*g_j)@W1c + pre_i + pre_j + phi + b1) --
__global__ __launch_bounds__(320, 5) void h1_kernel(
    const float* __restrict__ g, const float* __restrict__ pre,
    const float* __restrict__ phiW, const float* __restrict__ Wp,
    const float* __restrict__ b1p,
    const int* __restrict__ mI, const int* __restrict__ aI,
    const int* __restrict__ db, const int* __restrict__ ge, const int* __restrict__ sp,
    float* __restrict__ h1buf, int P) {
  __shared__ float qt[64][32];
  __shared__ float Wt[32][HPAD];
  __shared__ int sIi[64], sIj[64], sRd[64], sRg[64], sRs[64];
  const int t = threadIdx.x;
  const int p0 = blockIdx.x * 64;
  const int c = t % 40, r = t / 40;
  if (t < 64) {
    int p = p0 + t;
    sIi[t] = mI[p]; sIj[t] = aI[p];
    sRd[t] = db[p]; sRg[t] = 10 + ge[p]; sRs[t] = 18 + sp[p];
  }
  float acc[8][4];
#pragma unroll
  for (int i = 0; i < 8; ++i) { acc[i][0] = acc[i][1] = acc[i][2] = acc[i][3] = 0.f; }
  __syncthreads();

  // hoisted staging pointers
  const int rowA = t >> 3, q4A = t & 7;
  const int rowB = (t + 320) >> 3, q4B = (t + 320) & 7;
  const float* gAi = g + (size_t)sIi[rowA] * GI + 4 * q4A;
  const float* gAj = g + (size_t)sIj[rowA] * GI + 4 * q4A;
  const float* gBi = g + (size_t)sIi[rowB] * GI + 4 * q4B;
  const float* gBj = g + (size_t)sIj[rowB] * GI + 4 * q4B;
  float* qdA = &qt[rowA][4 * q4A];
  float* qdB = &qt[rowB][4 * q4B];
  const float* wsrc[4]; float* wdst[4];
#pragma unroll
  for (int rep = 0; rep < 4; ++rep) {
    int idx = rep * 320 + t;
    int row = idx / 40, c4 = idx % 40;
    wsrc[rep] = Wp + (size_t)row * WPC + 320 + 4 * c4;
    wdst[rep] = &Wt[row][4 * c4];
  }

#pragma unroll 1
  for (int d0 = 0; d0 < GI; d0 += 32) {
    {
      const float4 a = *(const float4*)(gAi + d0);
      const float4 b = *(const float4*)(gAj + d0);
      *(float4*)qdA = make_float4(a.x * b.x, a.y * b.y, a.z * b.z, a.w * b.w);
    }
    if (t < 192) {
      const float4 a = *(const float4*)(gBi + d0);
      const float4 b = *(const float4*)(gBj + d0);
      *(float4*)qdB = make_float4(a.x * b.x, a.y * b.y, a.z * b.z, a.w * b.w);
    }
#pragma unroll
    for (int rep = 0; rep < 4; ++rep)
      *(float4*)wdst[rep] = *(const float4*)(wsrc[rep] + (size_t)d0 * WPC);
    __syncthreads();
    MAC8(&qt[0][0], 32)
    __syncthreads();
  }

  const float4 bb = *(const float4*)&b1p[4 * c];
#pragma unroll
  for (int i = 0; i < 8; ++i) {
    int p = r * 8 + i;
    const float4 pi = *(const float4*)&pre[(size_t)sIi[p] * (2 * HPAD) + 4 * c];
    const float4 pj = *(const float4*)&pre[(size_t)sIj[p] * (2 * HPAD) + HPAD + 4 * c];
    const float4 fd = *(const float4*)&phiW[sRd[p] * HPAD + 4 * c];
    const float4 fg = *(const float4*)&phiW[sRg[p] * HPAD + 4 * c];
    const float4 fs = *(const float4*)&phiW[sRs[p] * HPAD + 4 * c];
    float4 o;
    o.x = fmaxf(acc[i][0] + bb.x + pi.x + pj.x + fd.x + fg.x + fs.x, 0.f);
    o.y = fmaxf(acc[i][1] + bb.y + pi.y + pj.y + fd.y + fg.y + fs.y, 0.f);
    o.z = fmaxf(acc[i][2] + bb.z + pi.z + pj.z + fd.z + fg.z + fs.z, 0.f);
    o.w = fmaxf(acc[i][3] + bb.w + pi.w + pj.w + fd.w + fg.w + fs.w, 0.f);
    *(float4*)&h1buf[(size_t)(p0 + p) * HPAD + 4 * c] = o;
  }
}

// ---------------- score[p] = relu(h1@W2 + b2) @ W3 + b3 ----------------------
__global__ __launch_bounds__(320, 5) void score2_kernel(
    const float* __restrict__ h1buf, const float* __restrict__ W2p,
    const float* __restrict__ b2p, const float* __restrict__ W3p,
    const float* __restrict__ b3, float* __restrict__ sOut, int P) {
  __shared__ float qt[64][32];
  __shared__ float Wt[32][HPAD];
  __shared__ float pr[64][41];
  const int t = threadIdx.x;
  const int p0 = blockIdx.x * 64;
  const int c = t % 40, r = t / 40;
  float acc[8][4];
#pragma unroll
  for (int i = 0; i < 8; ++i) { acc[i][0] = acc[i][1] = acc[i][2] = acc[i][3] = 0.f; }

  const int rowA = t >> 3, q4A = t & 7;
  const int rowB = (t + 320) >> 3, q4B = (t + 320) & 7;
  const float* hA = h1buf + (size_t)(p0 + rowA) * HPAD + 4 * q4A;
  const float* hB = h1buf + (size_t)(p0 + rowB) * HPAD + 4 * q4B;
  float* qdA = &qt[rowA][4 * q4A];
  float* qdB = &qt[rowB][4 * q4B];
  const float* wsrc[4]; float* wdst[4];
#pragma unroll
  for (int rep = 0; rep < 4; ++rep) {
    int idx = rep * 320 + t;
    int row = idx / 40, c4 = idx % 40;
    wsrc[rep] = W2p + (size_t)row * HPAD + 4 * c4;
    wdst[rep] = &Wt[row][4 * c4];
  }

#pragma unroll 1
  for (int k0 = 0; k0 < HPAD; k0 += 32) {
    if (k0) __syncthreads();
    *(float4*)qdA = *(const float4*)(hA + k0);
    if (t < 192) *(float4*)qdB = *(const float4*)(hB + k0);
#pragma unroll
    for (int rep = 0; rep < 4; ++rep)
      *(float4*)wdst[rep] = *(const float4*)(wsrc[rep] + (size_t)k0 * HPAD);
    __syncthreads();
    MAC8(&qt[0][0], 32)
  }

  const float4 bb = *(const float4*)&b2p[4 * c];
  const float4 w3 = *(const float4*)&W3p[4 * c];
#pragma unroll
  for (int i = 0; i < 8; ++i) {
    float partial =
      fmaxf(acc[i][0] + bb.x, 0.f) * w3.x + fmaxf(acc[i][1] + bb.y, 0.f) * w3.y +
      fmaxf(acc[i][2] + bb.z, 0.f) * w3.z + fmaxf(acc[i][3] + bb.w, 0.f) * w3.w;
    pr[r * 8 + i][c] = partial;
  }
  __syncthreads();
  if (t < 64) {
    float s = 0.f;
#pragma unroll
    for (int k = 0; k < 40; ++k) s += pr[t][k];
    sOut[p0 + t] = s + b3[0];
  }
}

// ---------------- mid: segment softmax -> weighted -> gated g update ----------
__global__ void mid_kernel(const float* __restrict__ g, const float* __restrict__ s1,
                           const int* __restrict__ segs, const int* __restrict__ aI,
                           const float* __restrict__ Wf, const float* __restrict__ bf,
                           float* __restrict__ g2) {
  const int m = blockIdx.x;
  const int t = threadIdx.x;  // 256
  const int st = segs[m], en = segs[m + 1], n = en - st;
  if (n == 0) {
    for (int d = t; d < GI; d += 256) g2[m * GI + d] = g[m * GI + d];
    return;
  }
  __shared__ float red[256];
  float mx = -INFINITY;
  for (int p = st + t; p < en; p += 256) mx = fmaxf(mx, s1[p]);
  red[t] = mx; __syncthreads();
  for (int s = 128; s > 0; s >>= 1) { if (t < s) red[t] = fmaxf(red[t], red[t + s]); __syncthreads(); }
  mx = red[0]; __syncthreads();
  float sm = 0.f;
  for (int p = st + t; p < en; p += 256) sm += expf(s1[p] - mx);
  red[t] = sm; __syncthreads();
  for (int s = 128; s > 0; s >>= 1) { if (t < s) red[t] += red[t + s]; __syncthreads(); }
  const float denom = red[0]; __syncthreads();
  float w[3] = {0.f, 0.f, 0.f};
  for (int p = st; p < en; ++p) {
    float e = expf(s1[p] - mx);
    const float* gj = g + aI[p] * GI;
#pragma unroll
    for (int u = 0; u < 3; ++u) w[u] += e * gj[t + u * 256];
  }
#pragma unroll
  for (int u = 0; u < 3; ++u) w[u] /= denom;
  float part = 0.f;
#pragma unroll
  for (int u = 0; u < 3; ++u) {
    int d = t + u * 256;
    part += g[m * GI + d] * Wf[d] + w[u] * Wf[GI + d];
  }
  red[t] = part; __syncthreads();
  for (int s = 128; s > 0; s >>= 1) { if (t < s) red[t] += red[t + s]; __syncthreads(); }
  const float f = 1.f / (1.f + expf(-(red[0] + bf[0])));
#pragma unroll
  for (int u = 0; u < 3; ++u) {
    int d = t + u * 256;
    g2[m * GI + d] = f * (float)m + (1.f - f) * w[u];
  }
}

// ---------------- coref_scores[p] = ms[i] + ms[j] + s2[p] ---------------------
__global__ void coref_kernel(const float* __restrict__ ms, const float* __restrict__ s2,
                             const int* __restrict__ mI, const int* __restrict__ aI,
                             float* __restrict__ out, int P) {
  int p = blockIdx.x * 256 + threadIdx.x;
  if (p >= P) return;
  out[p] = ms[mI[p]] + ms[aI[p]] + s2[p];
}

// ---------------- final segment softmax with epsilon --------------------------
__global__ void final_kernel(const float* __restrict__ c, const int* __restrict__ segs,
                             float* __restrict__ pairP, float* __restrict__ epsP) {
  const int m = blockIdx.x;
  const int t = threadIdx.x;  // 256
  const int st = segs[m], en = segs[m + 1], n = en - st;
  __shared__ float red[256];
  float mx = -INFINITY;
  for (int p = st + t; p < en; p += 256) mx = fmaxf(mx, c[p]);
  red[t] = mx; __syncthreads();
  for (int s = 128; s > 0; s >>= 1) { if (t < s) red[t] = fmaxf(red[t], red[t + s]); __syncthreads(); }
  mx = red[0]; __syncthreads();
  const float m2 = (n > 0) ? fmaxf(mx, 0.f) : 0.f;
  float sm = 0.f;
  for (int p = st + t; p < en; p += 256) sm += expf(c[p] - m2);
  red[t] = sm; __syncthreads();
  for (int s = 128; s > 0; s >>= 1) { if (t < s) red[t] += red[t + s]; __syncthreads(); }
  const float denom = red[0] + expf(-m2);
  for (int p = st + t; p < en; p += 256) pairP[p] = expf(c[p] - m2) / denom;
  if (t == 0) epsP[m] = expf(-m2) / denom;
}

extern "C" void kernel_launch(void* const* d_in, const int* in_sizes, int n_in,
                              void* d_out, int out_size, void* d_ws, size_t ws_size,
                              hipStream_t stream) {
  const float* g_i  = (const float*)d_in[0];
  const float* ms   = (const float*)d_in[1];
  const int*   mI   = (const int*)d_in[2];
  const int*   aI   = (const int*)d_in[3];
  const int*   db   = (const int*)d_in[4];
  const int*   ge   = (const int*)d_in[5];
  const int*   sp   = (const int*)d_in[6];
  const float* de   = (const float*)d_in[7];
  const float* gemb = (const float*)d_in[8];
  const float* semb = (const float*)d_in[9];
  const float* W1   = (const float*)d_in[10];
  const float* b1   = (const float*)d_in[11];
  const float* W2   = (const float*)d_in[12];
  const float* b2   = (const float*)d_in[13];
  const float* W3   = (const float*)d_in[14];
  const float* b3   = (const float*)d_in[15];
  const float* Wf   = (const float*)d_in[16];
  const float* bf   = (const float*)d_in[17];

  const int S = in_sizes[0] / GI;
  const int P = in_sizes[2];
  float* out = (float*)d_out;                 // [coref P | pairP P | epsP S]

  char* ws = (char*)d_ws;
  size_t off = 0;
  auto take = [&](size_t bytes) -> char* {
    char* p = ws + off;
    off = (off + bytes + 15) & ~(size_t)15;
    return p;
  };
  int*   segs = (int*)  take((size_t)(S + 1) * 4);
  float* phiW = (float*)take((size_t)21 * HPAD * 4);
  float* pre  = (float*)take((size_t)S * 2 * HPAD * 4);
  float* g2   = (float*)take((size_t)S * GI * 4);
  float* s1   = (float*)take((size_t)P * 4);
  float* s2   = (float*)take((size_t)P * 4);
  float* h1b  = (float*)take((size_t)P * HPAD * 4);
  float* Wp   = (float*)take((size_t)GI * WPC * 4);
  float* W2p  = (float*)take((size_t)HPAD * HPAD * 4);
  float* b1p  = (float*)take((size_t)HPAD * 4);
  float* b2p  = (float*)take((size_t)HPAD * 4);
  float* W3p  = (float*)take((size_t)HPAD * 4);

  const int gridSeg = (S + 1 + 255) / 256;
  const int gridPhi = (21 * HPAD + 255) / 256;
  const int gridPad = (GI * WPC + HPAD * HPAD + 3 * HPAD + 255) / 256;
  const dim3 gridPre((S + 63) / 64, 2);
  const int gridScr = P / 64;          // P % 64 == 0
  const int gridCor = (P + 255) / 256;

  seg_kernel<<<gridSeg, 256, 0, stream>>>(mI, segs, P, S);
  phi_kernel<<<gridPhi, 256, 0, stream>>>(de, gemb, semb, W1, phiW);
  pad_kernel<<<gridPad, 256, 0, stream>>>(W1, W2, b1, b2, W3, Wp, W2p, b1p, b2p, W3p);

  // iteration 1 (g = g_i)
  pre_kernel<<<gridPre, 320, 0, stream>>>(g_i, Wp, pre, S);
  h1_kernel<<<gridScr, 320, 0, stream>>>(g_i, pre, phiW, Wp, b1p,
                                         mI, aI, db, ge, sp, h1b, P);
  score2_kernel<<<gridScr, 320, 0, stream>>>(h1b, W2p, b2p, W3p, b3, s1, P);
  mid_kernel<<<S, 256, 0, stream>>>(g_i, s1, segs, aI, Wf, bf, g2);

  // iteration 2 (g = g2)
  pre_kernel<<<gridPre, 320, 0, stream>>>(g2, Wp, pre, S);
  h1_kernel<<<gridScr, 320, 0, stream>>>(g2, pre, phiW, Wp, b1p,
                                         mI, aI, db, ge, sp, h1b, P);
  score2_kernel<<<gridScr, 320, 0, stream>>>(h1b, W2p, b2p, W3p, b3, s2, P);

  // outputs
  coref_kernel<<<gridCor, 256, 0, stream>>>(ms, s2, mI, aI, out, P);
  final_kernel<<<S, 256, 0, stream>>>(out, segs, out + P, out + 2 * (size_t)P);
}

// Round 4
// 495.478 us; speedup vs baseline: 6.6536x; 2.3402x over previous
//
#include <hip/hip_runtime.h>

#define GI   768
#define HID  150
#define HPAD 160
#define DDIM 20

typedef __attribute__((ext_vector_type(8))) short v8s;
typedef __attribute__((ext_vector_type(16))) float f32x16;

#define MFMA(A, B, C) __builtin_amdgcn_mfma_f32_32x32x16_bf16(A, B, C, 0, 0, 0)

// round-to-nearest-even bf16 of f32
__device__ __forceinline__ ushort bf16rn(float x) {
  unsigned u = __float_as_uint(x);
  return (ushort)((u + 0x7fffu + ((u >> 16) & 1u)) >> 16);
}
// split x into hi + lo bf16 (residual ~2^-17 relative)
__device__ __forceinline__ void bsplit(float x, ushort& h, ushort& l) {
  h = bf16rn(x);
  float fh = __uint_as_float((unsigned)h << 16);
  l = bf16rn(x - fh);
}
__device__ __forceinline__ uint4 pack8(const ushort* v) {
  uint4 r;
  r.x = v[0] | ((unsigned)v[1] << 16); r.y = v[2] | ((unsigned)v[3] << 16);
  r.z = v[4] | ((unsigned)v[5] << 16); r.w = v[6] | ((unsigned)v[7] << 16);
  return r;
}

// q tile [64 rows][48 ushort stride], XOR-swizzled at 16B granularity
__device__ __forceinline__ int qoffb(int row, int kb) {
  return row * 96 + (kb ^ (((row >> 2) & 3) << 4));
}
// h1 tile [64 rows][168 ushort stride]
__device__ __forceinline__ int hoffb(int row, int kb) {
  return row * 336 + (kb ^ (((row >> 3) & 3) << 4));
}

// ---------------- segment boundaries ------------------------------------------
__global__ void seg_kernel(const int* __restrict__ mI, int* __restrict__ segs,
                           int P, int S) {
  int m = blockIdx.x * 256 + threadIdx.x;
  if (m > S) return;
  int lo = 0, hi = P;
  while (lo < hi) { int mid = (lo + hi) >> 1; if (mI[mid] < m) lo = mid + 1; else hi = mid; }
  segs[m] = lo;
}

// ---------------- phi lookup tables: phiW[21][HPAD] f32 -----------------------
__global__ void phi_kernel(const float* __restrict__ de, const float* __restrict__ ge,
                           const float* __restrict__ se, const float* __restrict__ W1,
                           float* __restrict__ phiW) {
  int idx = blockIdx.x * 256 + threadIdx.x;
  if (idx >= 21 * HPAD) return;
  int row = idx / HPAD, h = idx % HPAD;
  float v = 0.f;
  if (h < HID) {
    const float* emb; int off;
    if (row < 10)      { emb = de + row * DDIM;        off = 0; }
    else if (row < 18) { emb = ge + (row - 10) * DDIM; off = DDIM; }
    else               { emb = se + (row - 18) * DDIM; off = 2 * DDIM; }
    for (int k = 0; k < DDIM; ++k) v += emb[k] * W1[(3 * GI + off + k) * HID + h];
  }
  phiW[row * HPAD + h] = v;
}

// ---------------- split weights into transposed bf16 hi/lo --------------------
// WT[480][768]: row c = seg*160+h holds W1[(seg*GI + r)*HID + h] over r
// W2T[160][160]: row c holds W2[k*HID + c] over k
__global__ void pad2_kernel(const float* __restrict__ W1, const float* __restrict__ W2,
                            const float* __restrict__ b1, const float* __restrict__ b2,
                            const float* __restrict__ W3,
                            ushort* __restrict__ WThi, ushort* __restrict__ WTlo,
                            ushort* __restrict__ W2Thi, ushort* __restrict__ W2Tlo,
                            float* __restrict__ b1p, float* __restrict__ b2p,
                            float* __restrict__ W3p) {
  int idx = blockIdx.x * 256 + threadIdx.x;
  if (idx < 480 * GI) {
    int c = idx / GI, r = idx % GI;
    int seg = c / HPAD, h = c % HPAD;
    float x = (h < HID) ? W1[(size_t)(seg * GI + r) * HID + h] : 0.f;
    ushort hh, ll; bsplit(x, hh, ll);
    WThi[idx] = hh; WTlo[idx] = ll; return;
  }
  idx -= 480 * GI;
  if (idx < HPAD * HPAD) {
    int c = idx / HPAD, k = idx % HPAD;
    float x = (c < HID && k < HID) ? W2[(size_t)k * HID + c] : 0.f;
    ushort hh, ll; bsplit(x, hh, ll);
    W2Thi[idx] = hh; W2Tlo[idx] = ll; return;
  }
  idx -= HPAD * HPAD;
  if (idx < HPAD) { b1p[idx] = (idx < HID) ? b1[idx] : 0.f; return; }
  idx -= HPAD;
  if (idx < HPAD) { b2p[idx] = (idx < HID) ? b2[idx] : 0.f; return; }
  idx -= HPAD;
  if (idx < HPAD) { W3p[idx] = (idx < HID) ? W3[idx] : 0.f; return; }
}

// ---------------- pre[s][0:160]=g@W1a, pre[s][160:320]=g@W1b via MFMA ---------
__global__ __launch_bounds__(320, 4) void pre2_kernel(
    const float* __restrict__ g, const ushort* __restrict__ WThi,
    const ushort* __restrict__ WTlo, float* __restrict__ pre, int S) {
  __shared__ char pool[12288];
  ushort* qhi = (ushort*)pool;          // [64][48]
  ushort* qlo = qhi + 64 * 48;
  const int t = threadIdx.x;
  const int lane = t & 63, w = t >> 6;
  const int lcol = lane & 31, half = lane >> 5;
  const int row0 = blockIdx.x * 64;
  const int hb = blockIdx.y * HPAD;     // 0 (A part) or 160 (B part)

  f32x16 acc0 = {}, acc1 = {};
  const ushort* wh = WThi + (size_t)(hb + w * 32 + lcol) * GI + 8 * half;
  const ushort* wl = WTlo + (size_t)(hb + w * 32 + lcol) * GI + 8 * half;

  const int qr = (t < 256) ? (t >> 2) : 0;
  const int kq = (t & 3) * 8;
  int srow = row0 + qr; if (srow >= S) srow = S - 1;
  const float* gp = g + (size_t)srow * GI + kq;
  char* qdH = (char*)qhi + qoffb(qr, kq * 2);
  char* qdL = (char*)qlo + qoffb(qr, kq * 2);

  for (int d0 = 0; d0 < GI; d0 += 32) {
    if (d0) __syncthreads();
    if (t < 256) {
      float4 a0 = *(const float4*)(gp + d0), a1 = *(const float4*)(gp + d0 + 4);
      float xr[8] = {a0.x, a0.y, a0.z, a0.w, a1.x, a1.y, a1.z, a1.w};
      ushort hs[8], ls[8];
#pragma unroll
      for (int j = 0; j < 8; ++j) bsplit(xr[j], hs[j], ls[j]);
      *(uint4*)qdH = pack8(hs); *(uint4*)qdL = pack8(ls);
    }
    __syncthreads();
#pragma unroll
    for (int kh = 0; kh < 2; ++kh) {
      v8s bh = *(const v8s*)(wh + d0 + 16 * kh);
      v8s bl = *(const v8s*)(wl + d0 + 16 * kh);
      const int kb = 32 * kh + 16 * half;
      v8s a0h = *(const v8s*)((char*)qhi + qoffb(lcol, kb));
      v8s a0l = *(const v8s*)((char*)qlo + qoffb(lcol, kb));
      acc0 = MFMA(a0h, bh, acc0); acc0 = MFMA(a0l, bh, acc0); acc0 = MFMA(a0h, bl, acc0);
      v8s a1h = *(const v8s*)((char*)qhi + qoffb(32 + lcol, kb));
      v8s a1l = *(const v8s*)((char*)qlo + qoffb(32 + lcol, kb));
      acc1 = MFMA(a1h, bh, acc1); acc1 = MFMA(a1l, bh, acc1); acc1 = MFMA(a1h, bl, acc1);
    }
  }
  const int h = w * 32 + lcol;
#pragma unroll
  for (int q = 0; q < 16; ++q) {
    int p = (q & 3) + 8 * (q >> 2) + 4 * half;
    int s0 = row0 + p;
    if (s0 < S) pre[(size_t)s0 * 320 + hb + h] = acc0[q];
    int s1 = row0 + 32 + p;
    if (s1 < S) pre[(size_t)s1 * 320 + hb + h] = acc1[q];
  }
}

// ---------------- fused per-pair MLP via MFMA ---------------------------------
// phase 1: h1 = relu((g_i.*g_j)@W1c + pre_i + pre_j + phi + b1)  -> LDS (bf16 hi/lo)
// phase 2: score = relu(h1@W2 + b2) @ W3 + b3
__global__ __launch_bounds__(320, 4) void h1s_kernel(
    const float* __restrict__ g, const float* __restrict__ pre,
    const float* __restrict__ phiW,
    const ushort* __restrict__ WThi, const ushort* __restrict__ WTlo,
    const ushort* __restrict__ W2Thi, const ushort* __restrict__ W2Tlo,
    const float* __restrict__ b1p, const float* __restrict__ b2p,
    const float* __restrict__ W3p, const float* __restrict__ b3,
    const int* __restrict__ mI, const int* __restrict__ aI,
    const int* __restrict__ db, const int* __restrict__ ge, const int* __restrict__ sp,
    float* __restrict__ sOut, int P) {
  __shared__ char pool[43008];
  __shared__ int sIi[64], sIj[64], sRd[64], sRg[64], sRs[64];
  __shared__ float sRed[64];
  ushort* qhi = (ushort*)pool;          // [64][48]  (phase 1)
  ushort* qlo = qhi + 64 * 48;
  ushort* thi = (ushort*)pool;          // [64][168] (phase 2, overlays q)
  ushort* tlo = thi + 64 * 168;

  const int t = threadIdx.x;
  const int lane = t & 63, w = t >> 6;
  const int lcol = lane & 31, half = lane >> 5;
  const int p0 = blockIdx.x * 64;

  if (t < 64) {
    int p = p0 + t;
    sIi[t] = mI[p]; sIj[t] = aI[p];
    sRd[t] = db[p]; sRg[t] = 10 + ge[p]; sRs[t] = 18 + sp[p];
    sRed[t] = 0.f;
  }

  f32x16 acc0 = {}, acc1 = {};
  const ushort* wh = WThi + (size_t)(320 + w * 32 + lcol) * GI + 8 * half;
  const ushort* wl = WTlo + (size_t)(320 + w * 32 + lcol) * GI + 8 * half;

  __syncthreads();

  const int qr = (t < 256) ? (t >> 2) : 0;
  const int kq = (t & 3) * 8;
  const float* gi = g + (size_t)sIi[qr] * GI + kq;
  const float* gj = g + (size_t)sIj[qr] * GI + kq;
  char* qdH = (char*)qhi + qoffb(qr, kq * 2);
  char* qdL = (char*)qlo + qoffb(qr, kq * 2);

  // ---- phase 1: q = g_i .* g_j, acc += q @ W1c (bf16 hi/lo, 3 MFMAs) ----
  for (int d0 = 0; d0 < GI; d0 += 32) {
    if (d0) __syncthreads();
    if (t < 256) {
      float4 a0 = *(const float4*)(gi + d0), a1 = *(const float4*)(gi + d0 + 4);
      float4 b0 = *(const float4*)(gj + d0), b1v = *(const float4*)(gj + d0 + 4);
      float xr[8] = {a0.x * b0.x, a0.y * b0.y, a0.z * b0.z, a0.w * b0.w,
                     a1.x * b1v.x, a1.y * b1v.y, a1.z * b1v.z, a1.w * b1v.w};
      ushort hs[8], ls[8];
#pragma unroll
      for (int j = 0; j < 8; ++j) bsplit(xr[j], hs[j], ls[j]);
      *(uint4*)qdH = pack8(hs); *(uint4*)qdL = pack8(ls);
    }
    __syncthreads();
#pragma unroll
    for (int kh = 0; kh < 2; ++kh) {
      v8s bh = *(const v8s*)(wh + d0 + 16 * kh);
      v8s bl = *(const v8s*)(wl + d0 + 16 * kh);
      const int kb = 32 * kh + 16 * half;
      v8s a0h = *(const v8s*)((char*)qhi + qoffb(lcol, kb));
      v8s a0l = *(const v8s*)((char*)qlo + qoffb(lcol, kb));
      acc0 = MFMA(a0h, bh, acc0); acc0 = MFMA(a0l, bh, acc0); acc0 = MFMA(a0h, bl, acc0);
      v8s a1h = *(const v8s*)((char*)qhi + qoffb(32 + lcol, kb));
      v8s a1l = *(const v8s*)((char*)qlo + qoffb(32 + lcol, kb));
      acc1 = MFMA(a1h, bh, acc1); acc1 = MFMA(a1l, bh, acc1); acc1 = MFMA(a1h, bl, acc1);
    }
  }
  __syncthreads();   // phase-1 LDS reads done; h1 tile overlays q tile

  // ---- epilogue 1: add pre_i + pre_j + phi + b1, relu, stash bf16 hi/lo ----
  const int h = w * 32 + lcol;
  const float b1v = b1p[h];
#pragma unroll
  for (int q = 0; q < 16; ++q) {
    const int rr = (q & 3) + 8 * (q >> 2) + 4 * half;
    {
      int p = rr;
      float v = acc0[q] + b1v
              + pre[(size_t)sIi[p] * 320 + h] + pre[(size_t)sIj[p] * 320 + 160 + h]
              + phiW[sRd[p] * HPAD + h] + phiW[sRg[p] * HPAD + h] + phiW[sRs[p] * HPAD + h];
      v = fmaxf(v, 0.f);
      ushort hh, ll; bsplit(v, hh, ll);
      *(ushort*)((char*)thi + hoffb(p, 2 * h)) = hh;
      *(ushort*)((char*)tlo + hoffb(p, 2 * h)) = ll;
    }
    {
      int p = 32 + rr;
      float v = acc1[q] + b1v
              + pre[(size_t)sIi[p] * 320 + h] + pre[(size_t)sIj[p] * 320 + 160 + h]
              + phiW[sRd[p] * HPAD + h] + phiW[sRg[p] * HPAD + h] + phiW[sRs[p] * HPAD + h];
      v = fmaxf(v, 0.f);
      ushort hh, ll; bsplit(v, hh, ll);
      *(ushort*)((char*)thi + hoffb(p, 2 * h)) = hh;
      *(ushort*)((char*)tlo + hoffb(p, 2 * h)) = ll;
    }
  }
  __syncthreads();

  // ---- phase 2: h2 = relu(h1 @ W2 + b2); score = h2 @ W3 ----
  f32x16 c0 = {}, c1 = {};
  const ushort* u2h = W2Thi + (size_t)(w * 32 + lcol) * HPAD + 8 * half;
  const ushort* u2l = W2Tlo + (size_t)(w * 32 + lcol) * HPAD + 8 * half;
#pragma unroll
  for (int c = 0; c < HPAD; c += 32) {
#pragma unroll
    for (int kh = 0; kh < 2; ++kh) {
      v8s bh = *(const v8s*)(u2h + c + 16 * kh);
      v8s bl = *(const v8s*)(u2l + c + 16 * kh);
      const int kb = 2 * (c + 16 * kh) + 16 * half;
      v8s a0h = *(const v8s*)((char*)thi + hoffb(lcol, kb));
      v8s a0l = *(const v8s*)((char*)tlo + hoffb(lcol, kb));
      c0 = MFMA(a0h, bh, c0); c0 = MFMA(a0l, bh, c0); c0 = MFMA(a0h, bl, c0);
      v8s a1h = *(const v8s*)((char*)thi + hoffb(32 + lcol, kb));
      v8s a1l = *(const v8s*)((char*)tlo + hoffb(32 + lcol, kb));
      c1 = MFMA(a1h, bh, c1); c1 = MFMA(a1l, bh, c1); c1 = MFMA(a1h, bl, c1);
    }
  }

  // ---- epilogue 2: relu(h2 + b2) * W3, reduce over h ----
  const float b2v = b2p[h], w3v = W3p[h];
#pragma unroll
  for (int q = 0; q < 16; ++q) {
    float v0 = fmaxf(c0[q] + b2v, 0.f) * w3v;
    float v1 = fmaxf(c1[q] + b2v, 0.f) * w3v;
#pragma unroll
    for (int m = 16; m; m >>= 1) {
      v0 += __shfl_xor(v0, m, 32);
      v1 += __shfl_xor(v1, m, 32);
    }
    if (lcol == 0) {
      const int rr = (q & 3) + 8 * (q >> 2) + 4 * half;
      atomicAdd(&sRed[rr], v0);
      atomicAdd(&sRed[32 + rr], v1);
    }
  }
  __syncthreads();
  if (t < 64) sOut[p0 + t] = sRed[t] + b3[0];
}

// ---------------- mid: segment softmax -> weighted -> gated g update ----------
__global__ void mid_kernel(const float* __restrict__ g, const float* __restrict__ s1,
                           const int* __restrict__ segs, const int* __restrict__ aI,
                           const float* __restrict__ Wf, const float* __restrict__ bf,
                           float* __restrict__ g2) {
  const int m = blockIdx.x;
  const int t = threadIdx.x;  // 256
  const int st = segs[m], en = segs[m + 1], n = en - st;
  if (n == 0) {
    for (int d = t; d < GI; d += 256) g2[m * GI + d] = g[m * GI + d];
    return;
  }
  __shared__ float red[256];
  float mx = -INFINITY;
  for (int p = st + t; p < en; p += 256) mx = fmaxf(mx, s1[p]);
  red[t] = mx; __syncthreads();
  for (int s = 128; s > 0; s >>= 1) { if (t < s) red[t] = fmaxf(red[t], red[t + s]); __syncthreads(); }
  mx = red[0]; __syncthreads();
  float sm = 0.f;
  for (int p = st + t; p < en; p += 256) sm += expf(s1[p] - mx);
  red[t] = sm; __syncthreads();
  for (int s = 128; s > 0; s >>= 1) { if (t < s) red[t] += red[t + s]; __syncthreads(); }
  const float denom = red[0]; __syncthreads();
  float wv[3] = {0.f, 0.f, 0.f};
  for (int p = st; p < en; ++p) {
    float e = expf(s1[p] - mx);
    const float* gj = g + (size_t)aI[p] * GI;
#pragma unroll
    for (int u = 0; u < 3; ++u) wv[u] += e * gj[t + u * 256];
  }
#pragma unroll
  for (int u = 0; u < 3; ++u) wv[u] /= denom;
  float part = 0.f;
#pragma unroll
  for (int u = 0; u < 3; ++u) {
    int d = t + u * 256;
    part += g[m * GI + d] * Wf[d] + wv[u] * Wf[GI + d];
  }
  red[t] = part; __syncthreads();
  for (int s = 128; s > 0; s >>= 1) { if (t < s) red[t] += red[t + s]; __syncthreads(); }
  const float f = 1.f / (1.f + expf(-(red[0] + bf[0])));
#pragma unroll
  for (int u = 0; u < 3; ++u) {
    int d = t + u * 256;
    g2[m * GI + d] = f * (float)m + (1.f - f) * wv[u];
  }
}

// ---------------- coref_scores[p] = ms[i] + ms[j] + s2[p] ---------------------
__global__ void coref_kernel(const float* __restrict__ ms, const float* __restrict__ s2,
                             const int* __restrict__ mI, const int* __restrict__ aI,
                             float* __restrict__ out, int P) {
  int p = blockIdx.x * 256 + threadIdx.x;
  if (p >= P) return;
  out[p] = ms[mI[p]] + ms[aI[p]] + s2[p];
}

// ---------------- final segment softmax with epsilon --------------------------
__global__ void final_kernel(const float* __restrict__ c, const int* __restrict__ segs,
                             float* __restrict__ pairP, float* __restrict__ epsP) {
  const int m = blockIdx.x;
  const int t = threadIdx.x;  // 256
  const int st = segs[m], en = segs[m + 1], n = en - st;
  __shared__ float red[256];
  float mx = -INFINITY;
  for (int p = st + t; p < en; p += 256) mx = fmaxf(mx, c[p]);
  red[t] = mx; __syncthreads();
  for (int s = 128; s > 0; s >>= 1) { if (t < s) red[t] = fmaxf(red[t], red[t + s]); __syncthreads(); }
  mx = red[0]; __syncthreads();
  const float m2 = (n > 0) ? fmaxf(mx, 0.f) : 0.f;
  float sm = 0.f;
  for (int p = st + t; p < en; p += 256) sm += expf(c[p] - m2);
  red[t] = sm; __syncthreads();
  for (int s = 128; s > 0; s >>= 1) { if (t < s) red[t] += red[t + s]; __syncthreads(); }
  const float denom = red[0] + expf(-m2);
  for (int p = st + t; p < en; p += 256) pairP[p] = expf(c[p] - m2) / denom;
  if (t == 0) epsP[m] = expf(-m2) / denom;
}

extern "C" void kernel_launch(void* const* d_in, const int* in_sizes, int n_in,
                              void* d_out, int out_size, void* d_ws, size_t ws_size,
                              hipStream_t stream) {
  const float* g_i  = (const float*)d_in[0];
  const float* ms   = (const float*)d_in[1];
  const int*   mI   = (const int*)d_in[2];
  const int*   aI   = (const int*)d_in[3];
  const int*   db   = (const int*)d_in[4];
  const int*   ge   = (const int*)d_in[5];
  const int*   sp   = (const int*)d_in[6];
  const float* de   = (const float*)d_in[7];
  const float* gemb = (const float*)d_in[8];
  const float* semb = (const float*)d_in[9];
  const float* W1   = (const float*)d_in[10];
  const float* b1   = (const float*)d_in[11];
  const float* W2   = (const float*)d_in[12];
  const float* b2   = (const float*)d_in[13];
  const float* W3   = (const float*)d_in[14];
  const float* b3   = (const float*)d_in[15];
  const float* Wf   = (const float*)d_in[16];
  const float* bf   = (const float*)d_in[17];

  const int S = in_sizes[0] / GI;
  const int P = in_sizes[2];
  float* out = (float*)d_out;                 // [coref P | pairP P | epsP S]

  char* ws = (char*)d_ws;
  size_t off = 0;
  auto take = [&](size_t bytes) -> char* {
    char* p = ws + off;
    off = (off + bytes + 15) & ~(size_t)15;
    return p;
  };
  int*    segs  = (int*)   take((size_t)(S + 1) * 4);
  float*  phiW  = (float*) take((size_t)21 * HPAD * 4);
  float*  pre   = (float*) take((size_t)S * 320 * 4);
  float*  g2    = (float*) take((size_t)S * GI * 4);
  float*  s1    = (float*) take((size_t)P * 4);
  float*  s2    = (float*) take((size_t)P * 4);
  ushort* WThi  = (ushort*)take((size_t)480 * GI * 2);
  ushort* WTlo  = (ushort*)take((size_t)480 * GI * 2);
  ushort* W2Thi = (ushort*)take((size_t)HPAD * HPAD * 2);
  ushort* W2Tlo = (ushort*)take((size_t)HPAD * HPAD * 2);
  float*  b1p   = (float*) take((size_t)HPAD * 4);
  float*  b2p   = (float*) take((size_t)HPAD * 4);
  float*  W3p   = (float*) take((size_t)HPAD * 4);

  const int gridSeg = (S + 1 + 255) / 256;
  const int gridPhi = (21 * HPAD + 255) / 256;
  const int gridPad = (480 * GI + HPAD * HPAD + 3 * HPAD + 255) / 256;
  const dim3 gridPre((S + 63) / 64, 2);
  const int gridH   = P / 64;          // P % 64 == 0
  const int gridCor = (P + 255) / 256;

  seg_kernel<<<gridSeg, 256, 0, stream>>>(mI, segs, P, S);
  phi_kernel<<<gridPhi, 256, 0, stream>>>(de, gemb, semb, W1, phiW);
  pad2_kernel<<<gridPad, 256, 0, stream>>>(W1, W2, b1, b2, W3,
                                           WThi, WTlo, W2Thi, W2Tlo, b1p, b2p, W3p);

  // iteration 1 (g = g_i)
  pre2_kernel<<<gridPre, 320, 0, stream>>>(g_i, WThi, WTlo, pre, S);
  h1s_kernel<<<gridH, 320, 0, stream>>>(g_i, pre, phiW, WThi, WTlo, W2Thi, W2Tlo,
                                        b1p, b2p, W3p, b3, mI, aI, db, ge, sp, s1, P);
  mid_kernel<<<S, 256, 0, stream>>>(g_i, s1, segs, aI, Wf, bf, g2);

  // iteration 2 (g = g2)
  pre2_kernel<<<gridPre, 320, 0, stream>>>(g2, WThi, WTlo, pre, S);
  h1s_kernel<<<gridH, 320, 0, stream>>>(g2, pre, phiW, WThi, WTlo, W2Thi, W2Tlo,
                                        b1p, b2p, W3p, b3, mI, aI, db, ge, sp, s2, P);

  // outputs
  coref_kernel<<<gridCor, 256, 0, stream>>>(ms, s2, mI, aI, out, P);
  final_kernel<<<S, 256, 0, stream>>>(out, segs, out + P, out + 2 * (size_t)P);
}

// Round 5
// 449.150 us; speedup vs baseline: 7.3399x; 1.1031x over previous
//
#include <hip/hip_runtime.h>

#define GI   768
#define HID  150
#define HPAD 160
#define DDIM 20

typedef __attribute__((ext_vector_type(8))) short v8s;
typedef __attribute__((ext_vector_type(16))) float f32x16;

#define MFMA(A, B, C) __builtin_amdgcn_mfma_f32_32x32x16_bf16(A, B, C, 0, 0, 0)

// round-to-nearest-even bf16 of f32
__device__ __forceinline__ ushort bf16rn(float x) {
  unsigned u = __float_as_uint(x);
  return (ushort)((u + 0x7fffu + ((u >> 16) & 1u)) >> 16);
}
// split x into hi + lo bf16 (residual ~2^-17 relative)
__device__ __forceinline__ void bsplit(float x, ushort& h, ushort& l) {
  h = bf16rn(x);
  float fh = __uint_as_float((unsigned)h << 16);
  l = bf16rn(x - fh);
}
__device__ __forceinline__ uint4 pack8(const ushort* v) {
  uint4 r;
  r.x = v[0] | ((unsigned)v[1] << 16); r.y = v[2] | ((unsigned)v[3] << 16);
  r.z = v[4] | ((unsigned)v[5] << 16); r.w = v[6] | ((unsigned)v[7] << 16);
  return r;
}

// q tile [64 rows][48 ushort stride], XOR-swizzled at 16B granularity
__device__ __forceinline__ int qoffb(int row, int kb) {
  return row * 96 + (kb ^ (((row >> 2) & 3) << 4));
}
// h1 tile [64 rows][168 ushort stride]
__device__ __forceinline__ int hoffb(int row, int kb) {
  return row * 336 + (kb ^ (((row >> 3) & 3) << 4));
}

// ---------------- segment boundaries ------------------------------------------
__global__ void seg_kernel(const int* __restrict__ mI, int* __restrict__ segs,
                           int P, int S) {
  int m = blockIdx.x * 256 + threadIdx.x;
  if (m > S) return;
  int lo = 0, hi = P;
  while (lo < hi) { int mid = (lo + hi) >> 1; if (mI[mid] < m) lo = mid + 1; else hi = mid; }
  segs[m] = lo;
}

// ---------------- phi lookup tables: phiW[21][HPAD] f32 -----------------------
__global__ void phi_kernel(const float* __restrict__ de, const float* __restrict__ ge,
                           const float* __restrict__ se, const float* __restrict__ W1,
                           float* __restrict__ phiW) {
  int idx = blockIdx.x * 256 + threadIdx.x;
  if (idx >= 21 * HPAD) return;
  int row = idx / HPAD, h = idx % HPAD;
  float v = 0.f;
  if (h < HID) {
    const float* emb; int off;
    if (row < 10)      { emb = de + row * DDIM;        off = 0; }
    else if (row < 18) { emb = ge + (row - 10) * DDIM; off = DDIM; }
    else               { emb = se + (row - 18) * DDIM; off = 2 * DDIM; }
    for (int k = 0; k < DDIM; ++k) v += emb[k] * W1[(3 * GI + off + k) * HID + h];
  }
  phiW[row * HPAD + h] = v;
}

// ---------------- split weights into transposed bf16 hi/lo --------------------
__global__ void pad2_kernel(const float* __restrict__ W1, const float* __restrict__ W2,
                            const float* __restrict__ b1, const float* __restrict__ b2,
                            const float* __restrict__ W3,
                            ushort* __restrict__ WThi, ushort* __restrict__ WTlo,
                            ushort* __restrict__ W2Thi, ushort* __restrict__ W2Tlo,
                            float* __restrict__ b1p, float* __restrict__ b2p,
                            float* __restrict__ W3p) {
  int idx = blockIdx.x * 256 + threadIdx.x;
  if (idx < 480 * GI) {
    int c = idx / GI, r = idx % GI;
    int seg = c / HPAD, h = c % HPAD;
    float x = (h < HID) ? W1[(size_t)(seg * GI + r) * HID + h] : 0.f;
    ushort hh, ll; bsplit(x, hh, ll);
    WThi[idx] = hh; WTlo[idx] = ll; return;
  }
  idx -= 480 * GI;
  if (idx < HPAD * HPAD) {
    int c = idx / HPAD, k = idx % HPAD;
    float x = (c < HID && k < HID) ? W2[(size_t)k * HID + c] : 0.f;
    ushort hh, ll; bsplit(x, hh, ll);
    W2Thi[idx] = hh; W2Tlo[idx] = ll; return;
  }
  idx -= HPAD * HPAD;
  if (idx < HPAD) { b1p[idx] = (idx < HID) ? b1[idx] : 0.f; return; }
  idx -= HPAD;
  if (idx < HPAD) { b2p[idx] = (idx < HID) ? b2[idx] : 0.f; return; }
  idx -= HPAD;
  if (idx < HPAD) { W3p[idx] = (idx < HID) ? W3[idx] : 0.f; return; }
}

// ---------------- pre[s][0:160]=g@W1a, pre[s][160:320]=g@W1b via MFMA ---------
// software-pipelined: double-buffered q tile + register prefetch of g and W
__global__ __launch_bounds__(320, 4) void pre2_kernel(
    const float* __restrict__ g, const ushort* __restrict__ WThi,
    const ushort* __restrict__ WTlo, float* __restrict__ pre, int S) {
  __shared__ char pool[24576];          // 2 x (qhi[64][48] + qlo[64][48])
  const int t = threadIdx.x;
  const int lane = t & 63, w = t >> 6;
  const int lcol = lane & 31, half = lane >> 5;
  const int row0 = blockIdx.x * 64;
  const int hb = blockIdx.y * HPAD;     // 0 (A part) or 160 (B part)

  f32x16 acc0 = {}, acc1 = {};
  const ushort* wh = WThi + (size_t)(hb + w * 32 + lcol) * GI + 8 * half;
  const ushort* wl = WTlo + (size_t)(hb + w * 32 + lcol) * GI + 8 * half;

  const int qr = (t < 256) ? (t >> 2) : 0;
  const int qob = qoffb(qr, (t & 3) * 16);   // byte offset within buffer
  int srow = row0 + qr; if (srow >= S) srow = S - 1;
  const float* gp = g + (size_t)srow * GI + (t & 3) * 8;

  // ---- prologue: stage buf0 (d0 = 0), load W regs for d0 = 0 ----
  if (t < 256) {
    float4 a0 = *(const float4*)(gp), a1 = *(const float4*)(gp + 4);
    float xr[8] = {a0.x, a0.y, a0.z, a0.w, a1.x, a1.y, a1.z, a1.w};
    ushort hs[8], ls[8];
#pragma unroll
    for (int j = 0; j < 8; ++j) bsplit(xr[j], hs[j], ls[j]);
    *(uint4*)(pool + qob) = pack8(hs);
    *(uint4*)(pool + 6144 + qob) = pack8(ls);
  }
  v8s cwh0 = *(const v8s*)(wh), cwh1 = *(const v8s*)(wh + 16);
  v8s cwl0 = *(const v8s*)(wl), cwl1 = *(const v8s*)(wl + 16);
  __syncthreads();

  int cur = 0;
#pragma unroll 1
  for (int d0 = 0; d0 < GI; d0 += 32) {
    const bool has = (d0 + 32) < GI;
    const int dn = has ? d0 + 32 : 0;
    // prefetch next q + W into registers (in flight across MFMA phase)
    float4 na0, na1;
    if (t < 256) { na0 = *(const float4*)(gp + dn); na1 = *(const float4*)(gp + dn + 4); }
    v8s nwh0 = *(const v8s*)(wh + dn), nwh1 = *(const v8s*)(wh + dn + 16);
    v8s nwl0 = *(const v8s*)(wl + dn), nwl1 = *(const v8s*)(wl + dn + 16);

    const char* qh = pool + cur * 12288;
    const char* ql = qh + 6144;
    {
      const int kb = 16 * half;
      v8s a0h = *(const v8s*)(qh + qoffb(lcol, kb));
      v8s a0l = *(const v8s*)(ql + qoffb(lcol, kb));
      acc0 = MFMA(a0h, cwh0, acc0); acc0 = MFMA(a0l, cwh0, acc0); acc0 = MFMA(a0h, cwl0, acc0);
      v8s a1h = *(const v8s*)(qh + qoffb(32 + lcol, kb));
      v8s a1l = *(const v8s*)(ql + qoffb(32 + lcol, kb));
      acc1 = MFMA(a1h, cwh0, acc1); acc1 = MFMA(a1l, cwh0, acc1); acc1 = MFMA(a1h, cwl0, acc1);
    }
    {
      const int kb = 32 + 16 * half;
      v8s a0h = *(const v8s*)(qh + qoffb(lcol, kb));
      v8s a0l = *(const v8s*)(ql + qoffb(lcol, kb));
      acc0 = MFMA(a0h, cwh1, acc0); acc0 = MFMA(a0l, cwh1, acc0); acc0 = MFMA(a0h, cwl1, acc0);
      v8s a1h = *(const v8s*)(qh + qoffb(32 + lcol, kb));
      v8s a1l = *(const v8s*)(ql + qoffb(32 + lcol, kb));
      acc1 = MFMA(a1h, cwh1, acc1); acc1 = MFMA(a1l, cwh1, acc1); acc1 = MFMA(a1h, cwl1, acc1);
    }
    if (has && t < 256) {
      float xr[8] = {na0.x, na0.y, na0.z, na0.w, na1.x, na1.y, na1.z, na1.w};
      ushort hs[8], ls[8];
#pragma unroll
      for (int j = 0; j < 8; ++j) bsplit(xr[j], hs[j], ls[j]);
      char* dst = pool + (cur ^ 1) * 12288;
      *(uint4*)(dst + qob) = pack8(hs);
      *(uint4*)(dst + 6144 + qob) = pack8(ls);
    }
    cwh0 = nwh0; cwh1 = nwh1; cwl0 = nwl0; cwl1 = nwl1;
    __syncthreads();
    cur ^= 1;
  }

  const int h = w * 32 + lcol;
#pragma unroll
  for (int q = 0; q < 16; ++q) {
    int p = (q & 3) + 8 * (q >> 2) + 4 * half;
    int s0 = row0 + p;
    if (s0 < S) pre[(size_t)s0 * 320 + hb + h] = acc0[q];
    int s1 = row0 + 32 + p;
    if (s1 < S) pre[(size_t)s1 * 320 + hb + h] = acc1[q];
  }
}

// ---------------- fused per-pair MLP via MFMA (software-pipelined) ------------
__global__ __launch_bounds__(320, 4) void h1s_kernel(
    const float* __restrict__ g, const float* __restrict__ pre,
    const float* __restrict__ phiW,
    const ushort* __restrict__ WThi, const ushort* __restrict__ WTlo,
    const ushort* __restrict__ W2Thi, const ushort* __restrict__ W2Tlo,
    const float* __restrict__ b1p, const float* __restrict__ b2p,
    const float* __restrict__ W3p, const float* __restrict__ b3,
    const int* __restrict__ mI, const int* __restrict__ aI,
    const int* __restrict__ db, const int* __restrict__ ge, const int* __restrict__ sp,
    float* __restrict__ sOut, int P) {
  __shared__ char pool[43008];
  __shared__ int sIi[64], sIj[64], sRd[64], sRg[64], sRs[64];
  __shared__ float sRed[64];
  // phase 1: two q buffers at pool+0 / pool+12288, each {qhi 6144 | qlo 6144}
  // phase 2: thi/tlo [64][168] overlaying the whole pool
  ushort* thi = (ushort*)pool;
  ushort* tlo = thi + 64 * 168;

  const int t = threadIdx.x;
  const int lane = t & 63, w = t >> 6;
  const int lcol = lane & 31, half = lane >> 5;
  const int p0 = blockIdx.x * 64;

  if (t < 64) {
    int p = p0 + t;
    sIi[t] = mI[p]; sIj[t] = aI[p];
    sRd[t] = db[p]; sRg[t] = 10 + ge[p]; sRs[t] = 18 + sp[p];
    sRed[t] = 0.f;
  }

  f32x16 acc0 = {}, acc1 = {};
  const ushort* wh = WThi + (size_t)(320 + w * 32 + lcol) * GI + 8 * half;
  const ushort* wl = WTlo + (size_t)(320 + w * 32 + lcol) * GI + 8 * half;

  __syncthreads();

  const int qr = (t < 256) ? (t >> 2) : 0;
  const int qob = qoffb(qr, (t & 3) * 16);
  const float* gi = g + (size_t)sIi[qr] * GI + (t & 3) * 8;
  const float* gj = g + (size_t)sIj[qr] * GI + (t & 3) * 8;

  // ---- prologue: stage buf0 (d0 = 0), load W regs for d0 = 0 ----
  if (t < 256) {
    float4 a0 = *(const float4*)(gi), a1 = *(const float4*)(gi + 4);
    float4 b0 = *(const float4*)(gj), b1v = *(const float4*)(gj + 4);
    float xr[8] = {a0.x * b0.x, a0.y * b0.y, a0.z * b0.z, a0.w * b0.w,
                   a1.x * b1v.x, a1.y * b1v.y, a1.z * b1v.z, a1.w * b1v.w};
    ushort hs[8], ls[8];
#pragma unroll
    for (int j = 0; j < 8; ++j) bsplit(xr[j], hs[j], ls[j]);
    *(uint4*)(pool + qob) = pack8(hs);
    *(uint4*)(pool + 6144 + qob) = pack8(ls);
  }
  v8s cwh0 = *(const v8s*)(wh), cwh1 = *(const v8s*)(wh + 16);
  v8s cwl0 = *(const v8s*)(wl), cwl1 = *(const v8s*)(wl + 16);
  __syncthreads();

  // ---- phase 1 main loop: MFMA(buf[cur]) while staging buf[cur^1] ----
  int cur = 0;
#pragma unroll 1
  for (int d0 = 0; d0 < GI; d0 += 32) {
    const bool has = (d0 + 32) < GI;
    const int dn = has ? d0 + 32 : 0;
    float4 na0, na1, nb0, nb1;
    if (t < 256) {
      na0 = *(const float4*)(gi + dn); na1 = *(const float4*)(gi + dn + 4);
      nb0 = *(const float4*)(gj + dn); nb1 = *(const float4*)(gj + dn + 4);
    }
    v8s nwh0 = *(const v8s*)(wh + dn), nwh1 = *(const v8s*)(wh + dn + 16);
    v8s nwl0 = *(const v8s*)(wl + dn), nwl1 = *(const v8s*)(wl + dn + 16);

    const char* qh = pool + cur * 12288;
    const char* ql = qh + 6144;
    {
      const int kb = 16 * half;
      v8s a0h = *(const v8s*)(qh + qoffb(lcol, kb));
      v8s a0l = *(const v8s*)(ql + qoffb(lcol, kb));
      acc0 = MFMA(a0h, cwh0, acc0); acc0 = MFMA(a0l, cwh0, acc0); acc0 = MFMA(a0h, cwl0, acc0);
      v8s a1h = *(const v8s*)(qh + qoffb(32 + lcol, kb));
      v8s a1l = *(const v8s*)(ql + qoffb(32 + lcol, kb));
      acc1 = MFMA(a1h, cwh0, acc1); acc1 = MFMA(a1l, cwh0, acc1); acc1 = MFMA(a1h, cwl0, acc1);
    }
    {
      const int kb = 32 + 16 * half;
      v8s a0h = *(const v8s*)(qh + qoffb(lcol, kb));
      v8s a0l = *(const v8s*)(ql + qoffb(lcol, kb));
      acc0 = MFMA(a0h, cwh1, acc0); acc0 = MFMA(a0l, cwh1, acc0); acc0 = MFMA(a0h, cwl1, acc0);
      v8s a1h = *(const v8s*)(qh + qoffb(32 + lcol, kb));
      v8s a1l = *(const v8s*)(ql + qoffb(32 + lcol, kb));
      acc1 = MFMA(a1h, cwh1, acc1); acc1 = MFMA(a1l, cwh1, acc1); acc1 = MFMA(a1h, cwl1, acc1);
    }
    if (has && t < 256) {
      float xr[8] = {na0.x * nb0.x, na0.y * nb0.y, na0.z * nb0.z, na0.w * nb0.w,
                     na1.x * nb1.x, na1.y * nb1.y, na1.z * nb1.z, na1.w * nb1.w};
      ushort hs[8], ls[8];
#pragma unroll
      for (int j = 0; j < 8; ++j) bsplit(xr[j], hs[j], ls[j]);
      char* dst = pool + (cur ^ 1) * 12288;
      *(uint4*)(dst + qob) = pack8(hs);
      *(uint4*)(dst + 6144 + qob) = pack8(ls);
    }
    cwh0 = nwh0; cwh1 = nwh1; cwl0 = nwl0; cwl1 = nwl1;
    __syncthreads();
    cur ^= 1;
  }

  // ---- epilogue 1: add pre_i + pre_j + phi + b1, relu, stash bf16 hi/lo ----
  const int h = w * 32 + lcol;
  const float b1v = b1p[h];
#pragma unroll
  for (int q = 0; q < 16; ++q) {
    const int rr = (q & 3) + 8 * (q >> 2) + 4 * half;
    {
      int p = rr;
      float v = acc0[q] + b1v
              + pre[(size_t)sIi[p] * 320 + h] + pre[(size_t)sIj[p] * 320 + 160 + h]
              + phiW[sRd[p] * HPAD + h] + phiW[sRg[p] * HPAD + h] + phiW[sRs[p] * HPAD + h];
      v = fmaxf(v, 0.f);
      ushort hh, ll; bsplit(v, hh, ll);
      *(ushort*)((char*)thi + hoffb(p, 2 * h)) = hh;
      *(ushort*)((char*)tlo + hoffb(p, 2 * h)) = ll;
    }
    {
      int p = 32 + rr;
      float v = acc1[q] + b1v
              + pre[(size_t)sIi[p] * 320 + h] + pre[(size_t)sIj[p] * 320 + 160 + h]
              + phiW[sRd[p] * HPAD + h] + phiW[sRg[p] * HPAD + h] + phiW[sRs[p] * HPAD + h];
      v = fmaxf(v, 0.f);
      ushort hh, ll; bsplit(v, hh, ll);
      *(ushort*)((char*)thi + hoffb(p, 2 * h)) = hh;
      *(ushort*)((char*)tlo + hoffb(p, 2 * h)) = ll;
    }
  }
  __syncthreads();

  // ---- phase 2: h2 = relu(h1 @ W2 + b2); score = h2 @ W3 ----
  f32x16 c0 = {}, c1 = {};
  const ushort* u2h = W2Thi + (size_t)(w * 32 + lcol) * HPAD + 8 * half;
  const ushort* u2l = W2Tlo + (size_t)(w * 32 + lcol) * HPAD + 8 * half;
#pragma unroll
  for (int c = 0; c < HPAD; c += 32) {
#pragma unroll
    for (int kh = 0; kh < 2; ++kh) {
      v8s bh = *(const v8s*)(u2h + c + 16 * kh);
      v8s bl = *(const v8s*)(u2l + c + 16 * kh);
      const int kb = 2 * (c + 16 * kh) + 16 * half;
      v8s a0h = *(const v8s*)((char*)thi + hoffb(lcol, kb));
      v8s a0l = *(const v8s*)((char*)tlo + hoffb(lcol, kb));
      c0 = MFMA(a0h, bh, c0); c0 = MFMA(a0l, bh, c0); c0 = MFMA(a0h, bl, c0);
      v8s a1h = *(const v8s*)((char*)thi + hoffb(32 + lcol, kb));
      v8s a1l = *(const v8s*)((char*)tlo + hoffb(32 + lcol, kb));
      c1 = MFMA(a1h, bh, c1); c1 = MFMA(a1l, bh, c1); c1 = MFMA(a1h, bl, c1);
    }
  }

  // ---- epilogue 2: relu(h2 + b2) * W3, reduce over h ----
  const float b2v = b2p[h], w3v = W3p[h];
#pragma unroll
  for (int q = 0; q < 16; ++q) {
    float v0 = fmaxf(c0[q] + b2v, 0.f) * w3v;
    float v1 = fmaxf(c1[q] + b2v, 0.f) * w3v;
#pragma unroll
    for (int m = 16; m; m >>= 1) {
      v0 += __shfl_xor(v0, m, 32);
      v1 += __shfl_xor(v1, m, 32);
    }
    if (lcol == 0) {
      const int rr = (q & 3) + 8 * (q >> 2) + 4 * half;
      atomicAdd(&sRed[rr], v0);
      atomicAdd(&sRed[32 + rr], v1);
    }
  }
  __syncthreads();
  if (t < 64) sOut[p0 + t] = sRed[t] + b3[0];
}

// ---------------- mid: segment softmax -> weighted -> gated g update ----------
__global__ void mid_kernel(const float* __restrict__ g, const float* __restrict__ s1,
                           const int* __restrict__ segs, const int* __restrict__ aI,
                           const float* __restrict__ Wf, const float* __restrict__ bf,
                           float* __restrict__ g2) {
  const int m = blockIdx.x;
  const int t = threadIdx.x;  // 256
  const int st = segs[m], en = segs[m + 1], n = en - st;
  if (n == 0) {
    for (int d = t; d < GI; d += 256) g2[m * GI + d] = g[m * GI + d];
    return;
  }
  __shared__ float red[256];
  float mx = -INFINITY;
  for (int p = st + t; p < en; p += 256) mx = fmaxf(mx, s1[p]);
  red[t] = mx; __syncthreads();
  for (int s = 128; s > 0; s >>= 1) { if (t < s) red[t] = fmaxf(red[t], red[t + s]); __syncthreads(); }
  mx = red[0]; __syncthreads();
  float sm = 0.f;
  for (int p = st + t; p < en; p += 256) sm += expf(s1[p] - mx);
  red[t] = sm; __syncthreads();
  for (int s = 128; s > 0; s >>= 1) { if (t < s) red[t] += red[t + s]; __syncthreads(); }
  const float denom = red[0]; __syncthreads();
  float wv[3] = {0.f, 0.f, 0.f};
  for (int p = st; p < en; ++p) {
    float e = expf(s1[p] - mx);
    const float* gj = g + (size_t)aI[p] * GI;
#pragma unroll
    for (int u = 0; u < 3; ++u) wv[u] += e * gj[t + u * 256];
  }
#pragma unroll
  for (int u = 0; u < 3; ++u) wv[u] /= denom;
  float part = 0.f;
#pragma unroll
  for (int u = 0; u < 3; ++u) {
    int d = t + u * 256;
    part += g[m * GI + d] * Wf[d] + wv[u] * Wf[GI + d];
  }
  red[t] = part; __syncthreads();
  for (int s = 128; s > 0; s >>= 1) { if (t < s) red[t] += red[t + s]; __syncthreads(); }
  const float f = 1.f / (1.f + expf(-(red[0] + bf[0])));
#pragma unroll
  for (int u = 0; u < 3; ++u) {
    int d = t + u * 256;
    g2[m * GI + d] = f * (float)m + (1.f - f) * wv[u];
  }
}

// ---------------- coref_scores[p] = ms[i] + ms[j] + s2[p] ---------------------
__global__ void coref_kernel(const float* __restrict__ ms, const float* __restrict__ s2,
                             const int* __restrict__ mI, const int* __restrict__ aI,
                             float* __restrict__ out, int P) {
  int p = blockIdx.x * 256 + threadIdx.x;
  if (p >= P) return;
  out[p] = ms[mI[p]] + ms[aI[p]] + s2[p];
}

// ---------------- final segment softmax with epsilon --------------------------
__global__ void final_kernel(const float* __restrict__ c, const int* __restrict__ segs,
                             float* __restrict__ pairP, float* __restrict__ epsP) {
  const int m = blockIdx.x;
  const int t = threadIdx.x;  // 256
  const int st = segs[m], en = segs[m + 1], n = en - st;
  __shared__ float red[256];
  float mx = -INFINITY;
  for (int p = st + t; p < en; p += 256) mx = fmaxf(mx, c[p]);
  red[t] = mx; __syncthreads();
  for (int s = 128; s > 0; s >>= 1) { if (t < s) red[t] = fmaxf(red[t], red[t + s]); __syncthreads(); }
  mx = red[0]; __syncthreads();
  const float m2 = (n > 0) ? fmaxf(mx, 0.f) : 0.f;
  float sm = 0.f;
  for (int p = st + t; p < en; p += 256) sm += expf(c[p] - m2);
  red[t] = sm; __syncthreads();
  for (int s = 128; s > 0; s >>= 1) { if (t < s) red[t] += red[t + s]; __syncthreads(); }
  const float denom = red[0] + expf(-m2);
  for (int p = st + t; p < en; p += 256) pairP[p] = expf(c[p] - m2) / denom;
  if (t == 0) epsP[m] = expf(-m2) / denom;
}

extern "C" void kernel_launch(void* const* d_in, const int* in_sizes, int n_in,
                              void* d_out, int out_size, void* d_ws, size_t ws_size,
                              hipStream_t stream) {
  const float* g_i  = (const float*)d_in[0];
  const float* ms   = (const float*)d_in[1];
  const int*   mI   = (const int*)d_in[2];
  const int*   aI   = (const int*)d_in[3];
  const int*   db   = (const int*)d_in[4];
  const int*   ge   = (const int*)d_in[5];
  const int*   sp   = (const int*)d_in[6];
  const float* de   = (const float*)d_in[7];
  const float* gemb = (const float*)d_in[8];
  const float* semb = (const float*)d_in[9];
  const float* W1   = (const float*)d_in[10];
  const float* b1   = (const float*)d_in[11];
  const float* W2   = (const float*)d_in[12];
  const float* b2   = (const float*)d_in[13];
  const float* W3   = (const float*)d_in[14];
  const float* b3   = (const float*)d_in[15];
  const float* Wf   = (const float*)d_in[16];
  const float* bf   = (const float*)d_in[17];

  const int S = in_sizes[0] / GI;
  const int P = in_sizes[2];
  float* out = (float*)d_out;                 // [coref P | pairP P | epsP S]

  char* ws = (char*)d_ws;
  size_t off = 0;
  auto take = [&](size_t bytes) -> char* {
    char* p = ws + off;
    off = (off + bytes + 15) & ~(size_t)15;
    return p;
  };
  int*    segs  = (int*)   take((size_t)(S + 1) * 4);
  float*  phiW  = (float*) take((size_t)21 * HPAD * 4);
  float*  pre   = (float*) take((size_t)S * 320 * 4);
  float*  g2    = (float*) take((size_t)S * GI * 4);
  float*  s1    = (float*) take((size_t)P * 4);
  float*  s2    = (float*) take((size_t)P * 4);
  ushort* WThi  = (ushort*)take((size_t)480 * GI * 2);
  ushort* WTlo  = (ushort*)take((size_t)480 * GI * 2);
  ushort* W2Thi = (ushort*)take((size_t)HPAD * HPAD * 2);
  ushort* W2Tlo = (ushort*)take((size_t)HPAD * HPAD * 2);
  float*  b1p   = (float*) take((size_t)HPAD * 4);
  float*  b2p   = (float*) take((size_t)HPAD * 4);
  float*  W3p   = (float*) take((size_t)HPAD * 4);

  const int gridSeg = (S + 1 + 255) / 256;
  const int gridPhi = (21 * HPAD + 255) / 256;
  const int gridPad = (480 * GI + HPAD * HPAD + 3 * HPAD + 255) / 256;
  const dim3 gridPre((S + 63) / 64, 2);
  const int gridH   = P / 64;          // P % 64 == 0
  const int gridCor = (P + 255) / 256;

  seg_kernel<<<gridSeg, 256, 0, stream>>>(mI, segs, P, S);
  phi_kernel<<<gridPhi, 256, 0, stream>>>(de, gemb, semb, W1, phiW);
  pad2_kernel<<<gridPad, 256, 0, stream>>>(W1, W2, b1, b2, W3,
                                           WThi, WTlo, W2Thi, W2Tlo, b1p, b2p, W3p);

  // iteration 1 (g = g_i)
  pre2_kernel<<<gridPre, 320, 0, stream>>>(g_i, WThi, WTlo, pre, S);
  h1s_kernel<<<gridH, 320, 0, stream>>>(g_i, pre, phiW, WThi, WTlo, W2Thi, W2Tlo,
                                        b1p, b2p, W3p, b3, mI, aI, db, ge, sp, s1, P);
  mid_kernel<<<S, 256, 0, stream>>>(g_i, s1, segs, aI, Wf, bf, g2);

  // iteration 2 (g = g2)
  pre2_kernel<<<gridPre, 320, 0, stream>>>(g2, WThi, WTlo, pre, S);
  h1s_kernel<<<gridH, 320, 0, stream>>>(g2, pre, phiW, WThi, WTlo, W2Thi, W2Tlo,
                                        b1p, b2p, W3p, b3, mI, aI, db, ge, sp, s2, P);

  // outputs
  coref_kernel<<<gridCor, 256, 0, stream>>>(ms, s2, mI, aI, out, P);
  final_kernel<<<S, 256, 0, stream>>>(out, segs, out + P, out + 2 * (size_t)P);
}

// Round 6
// 397.614 us; speedup vs baseline: 8.2913x; 1.1296x over previous
//
#include <hip/hip_runtime.h>

#define GI   768
#define HID  150
#define HPAD 160
#define DDIM 20

typedef __attribute__((ext_vector_type(8))) short v8s;
typedef __attribute__((ext_vector_type(16))) float f32x16;

#define MFMA(A, B, C) __builtin_amdgcn_mfma_f32_32x32x16_bf16(A, B, C, 0, 0, 0)

// round-to-nearest-even bf16 of f32 (cold path: weight prep)
__device__ __forceinline__ ushort bf16rn(float x) {
  unsigned u = __float_as_uint(x);
  return (ushort)((u + 0x7fffu + ((u >> 16) & 1u)) >> 16);
}
__device__ __forceinline__ void bsplit(float x, ushort& h, ushort& l) {
  h = bf16rn(x);
  float fh = __uint_as_float((unsigned)h << 16);
  l = bf16rn(x - fh);
}
// truncation split (hot path): hi = trunc-bf16(x), lo = trunc-bf16(x - hi)
__device__ __forceinline__ void tsplit(float x, ushort& h, ushort& l) {
  unsigned u = __float_as_uint(x);
  h = (ushort)(u >> 16);
  float d = x - __uint_as_float(u & 0xffff0000u);
  l = (ushort)(__float_as_uint(d) >> 16);
}
__device__ __forceinline__ uint4 pack8(const ushort* v) {
  uint4 r;
  r.x = v[0] | ((unsigned)v[1] << 16); r.y = v[2] | ((unsigned)v[3] << 16);
  r.z = v[4] | ((unsigned)v[5] << 16); r.w = v[6] | ((unsigned)v[7] << 16);
  return r;
}
__device__ __forceinline__ v8s mk8(const ushort* v) {
  union { uint4 u; v8s s; } t;
  t.u = pack8(v);
  return t.s;
}

// q tile [64 rows][48 ushort stride], XOR-swizzled at 16B granularity (pre2 only)
__device__ __forceinline__ int qoffb(int row, int kb) {
  return row * 96 + (kb ^ (((row >> 2) & 3) << 4));
}

// ---------------- segment boundaries ------------------------------------------
__global__ void seg_kernel(const int* __restrict__ mI, int* __restrict__ segs,
                           int P, int S) {
  int m = blockIdx.x * 256 + threadIdx.x;
  if (m > S) return;
  int lo = 0, hi = P;
  while (lo < hi) { int mid = (lo + hi) >> 1; if (mI[mid] < m) lo = mid + 1; else hi = mid; }
  segs[m] = lo;
}

// ---------------- phi lookup tables: phiW[21][HPAD] f32 -----------------------
__global__ void phi_kernel(const float* __restrict__ de, const float* __restrict__ ge,
                           const float* __restrict__ se, const float* __restrict__ W1,
                           float* __restrict__ phiW) {
  int idx = blockIdx.x * 256 + threadIdx.x;
  if (idx >= 21 * HPAD) return;
  int row = idx / HPAD, h = idx % HPAD;
  float v = 0.f;
  if (h < HID) {
    const float* emb; int off;
    if (row < 10)      { emb = de + row * DDIM;        off = 0; }
    else if (row < 18) { emb = ge + (row - 10) * DDIM; off = DDIM; }
    else               { emb = se + (row - 18) * DDIM; off = 2 * DDIM; }
    for (int k = 0; k < DDIM; ++k) v += emb[k] * W1[(3 * GI + off + k) * HID + h];
  }
  phiW[row * HPAD + h] = v;
}

// ---------------- weight prep -------------------------------------------------
// WT[480][768] (pre2): row c = seg*160+h holds W1[(seg*GI+r)*HID+h] over r (seg 0,1)
// WB[5][48][512] (h1a): fragment-packed W1c — elem (c,s,l,j):
//     h = c*32+(l&31), k = s*16+8*(l>>5)+j, value W1[(2*GI+k)*HID+h]
// W2B[5][10][512] (score3): same packing of W2[k][h2]
__global__ void pad2_kernel(const float* __restrict__ W1, const float* __restrict__ W2,
                            const float* __restrict__ b1, const float* __restrict__ b2,
                            const float* __restrict__ W3,
                            ushort* __restrict__ WThi, ushort* __restrict__ WTlo,
                            ushort* __restrict__ WBhi, ushort* __restrict__ WBlo,
                            ushort* __restrict__ W2Bhi, ushort* __restrict__ W2Blo,
                            float* __restrict__ b1p, float2* __restrict__ b2w3) {
  int idx = blockIdx.x * 256 + threadIdx.x;
  if (idx < 480 * GI) {
    int c = idx / GI, r = idx % GI;
    int seg = c / HPAD, h = c % HPAD;
    float x = (h < HID) ? W1[(size_t)(seg * GI + r) * HID + h] : 0.f;
    ushort hh, ll; bsplit(x, hh, ll);
    WThi[idx] = hh; WTlo[idx] = ll; return;
  }
  idx -= 480 * GI;
  if (idx < 5 * 48 * 512) {
    int c = idx / (48 * 512); int r1 = idx % (48 * 512);
    int s = r1 / 512; int r2 = r1 % 512;
    int l = r2 / 8, j = r2 % 8;
    int h = c * 32 + (l & 31);
    int k = s * 16 + 8 * (l >> 5) + j;
    float x = (h < HID) ? W1[(size_t)(2 * GI + k) * HID + h] : 0.f;
    ushort hh, ll; bsplit(x, hh, ll);
    WBhi[idx] = hh; WBlo[idx] = ll; return;
  }
  idx -= 5 * 48 * 512;
  if (idx < 5 * 10 * 512) {
    int rt = idx / (10 * 512); int r1 = idx % (10 * 512);
    int s = r1 / 512; int r2 = r1 % 512;
    int l = r2 / 8, j = r2 % 8;
    int h2 = rt * 32 + (l & 31);
    int k = s * 16 + 8 * (l >> 5) + j;
    float x = (k < HID && h2 < HID) ? W2[(size_t)k * HID + h2] : 0.f;
    ushort hh, ll; bsplit(x, hh, ll);
    W2Bhi[idx] = hh; W2Blo[idx] = ll; return;
  }
  idx -= 5 * 10 * 512;
  if (idx < HPAD) { b1p[idx] = (idx < HID) ? b1[idx] : 0.f; return; }
  idx -= HPAD;
  if (idx < HPAD) {
    b2w3[idx] = make_float2((idx < HID) ? b2[idx] : 0.f, (idx < HID) ? W3[idx] : 0.f);
    return;
  }
}

// ---------------- pre[s][0:160]=g@W1a, pre[s][160:320]=g@W1b via MFMA ---------
// (unchanged from round 5 — software-pipelined LDS version)
__global__ __launch_bounds__(320, 4) void pre2_kernel(
    const float* __restrict__ g, const ushort* __restrict__ WThi,
    const ushort* __restrict__ WTlo, float* __restrict__ pre, int S) {
  __shared__ char pool[24576];
  const int t = threadIdx.x;
  const int lane = t & 63, w = t >> 6;
  const int lcol = lane & 31, half = lane >> 5;
  const int row0 = blockIdx.x * 64;
  const int hb = blockIdx.y * HPAD;

  f32x16 acc0 = {}, acc1 = {};
  const ushort* wh = WThi + (size_t)(hb + w * 32 + lcol) * GI + 8 * half;
  const ushort* wl = WTlo + (size_t)(hb + w * 32 + lcol) * GI + 8 * half;

  const int qr = (t < 256) ? (t >> 2) : 0;
  const int qob = qoffb(qr, (t & 3) * 16);
  int srow = row0 + qr; if (srow >= S) srow = S - 1;
  const float* gp = g + (size_t)srow * GI + (t & 3) * 8;

  if (t < 256) {
    float4 a0 = *(const float4*)(gp), a1 = *(const float4*)(gp + 4);
    float xr[8] = {a0.x, a0.y, a0.z, a0.w, a1.x, a1.y, a1.z, a1.w};
    ushort hs[8], ls[8];
#pragma unroll
    for (int j = 0; j < 8; ++j) bsplit(xr[j], hs[j], ls[j]);
    *(uint4*)(pool + qob) = pack8(hs);
    *(uint4*)(pool + 6144 + qob) = pack8(ls);
  }
  v8s cwh0 = *(const v8s*)(wh), cwh1 = *(const v8s*)(wh + 16);
  v8s cwl0 = *(const v8s*)(wl), cwl1 = *(const v8s*)(wl + 16);
  __syncthreads();

  int cur = 0;
#pragma unroll 1
  for (int d0 = 0; d0 < GI; d0 += 32) {
    const bool has = (d0 + 32) < GI;
    const int dn = has ? d0 + 32 : 0;
    float4 na0, na1;
    if (t < 256) { na0 = *(const float4*)(gp + dn); na1 = *(const float4*)(gp + dn + 4); }
    v8s nwh0 = *(const v8s*)(wh + dn), nwh1 = *(const v8s*)(wh + dn + 16);
    v8s nwl0 = *(const v8s*)(wl + dn), nwl1 = *(const v8s*)(wl + dn + 16);

    const char* qh = pool + cur * 12288;
    const char* ql = qh + 6144;
    {
      const int kb = 16 * half;
      v8s a0h = *(const v8s*)(qh + qoffb(lcol, kb));
      v8s a0l = *(const v8s*)(ql + qoffb(lcol, kb));
      acc0 = MFMA(a0h, cwh0, acc0); acc0 = MFMA(a0l, cwh0, acc0); acc0 = MFMA(a0h, cwl0, acc0);
      v8s a1h = *(const v8s*)(qh + qoffb(32 + lcol, kb));
      v8s a1l = *(const v8s*)(ql + qoffb(32 + lcol, kb));
      acc1 = MFMA(a1h, cwh0, acc1); acc1 = MFMA(a1l, cwh0, acc1); acc1 = MFMA(a1h, cwl0, acc1);
    }
    {
      const int kb = 32 + 16 * half;
      v8s a0h = *(const v8s*)(qh + qoffb(lcol, kb));
      v8s a0l = *(const v8s*)(ql + qoffb(lcol, kb));
      acc0 = MFMA(a0h, cwh1, acc0); acc0 = MFMA(a0l, cwh1, acc0); acc0 = MFMA(a0h, cwl1, acc0);
      v8s a1h = *(const v8s*)(qh + qoffb(32 + lcol, kb));
      v8s a1l = *(const v8s*)(ql + qoffb(32 + lcol, kb));
      acc1 = MFMA(a1h, cwh1, acc1); acc1 = MFMA(a1l, cwh1, acc1); acc1 = MFMA(a1h, cwl1, acc1);
    }
    if (has && t < 256) {
      float xr[8] = {na0.x, na0.y, na0.z, na0.w, na1.x, na1.y, na1.z, na1.w};
      ushort hs[8], ls[8];
#pragma unroll
      for (int j = 0; j < 8; ++j) bsplit(xr[j], hs[j], ls[j]);
      char* dst = pool + (cur ^ 1) * 12288;
      *(uint4*)(dst + qob) = pack8(hs);
      *(uint4*)(dst + 6144 + qob) = pack8(ls);
    }
    cwh0 = nwh0; cwh1 = nwh1; cwl0 = nwl0; cwl1 = nwl1;
    __syncthreads();
    cur ^= 1;
  }

  const int h = w * 32 + lcol;
#pragma unroll
  for (int q = 0; q < 16; ++q) {
    int p = (q & 3) + 8 * (q >> 2) + 4 * half;
    int s0 = row0 + p;
    if (s0 < S) pre[(size_t)s0 * 320 + hb + h] = acc0[q];
    int s1 = row0 + 32 + p;
    if (s1 < S) pre[(size_t)s1 * 320 + hb + h] = acc1[q];
  }
}

// ---------------- h1a: per-pair h1 GEMM, 1 wave/block, no LDS, no barriers ----
// block = 64 threads = 1 wave; 32 pairs x 160 cols; K = 768.
// A-fragment built in-register: lane holds row l&31, k-octet l>>5.
__global__ __launch_bounds__(64, 3) void h1a_kernel(
    const float* __restrict__ g, const float* __restrict__ pre,
    const float* __restrict__ phiW,
    const ushort* __restrict__ WBhi, const ushort* __restrict__ WBlo,
    const float* __restrict__ b1p,
    const int* __restrict__ mI, const int* __restrict__ aI,
    const int* __restrict__ db, const int* __restrict__ ge, const int* __restrict__ sp,
    ushort* __restrict__ h1hi, ushort* __restrict__ h1lo, int P) {
  const int lane = threadIdx.x;
  const int lcol = lane & 31, half = lane >> 5;
  const int p0 = blockIdx.x * 32;

  const int myp = p0 + lcol;
  const int iA = mI[myp], jA = aI[myp];
  const int rdL = db[myp], rgL = 10 + ge[myp], rsL = 18 + sp[myp];

  const float* gi = g + (size_t)iA * GI + 8 * half;
  const float* gj = g + (size_t)jA * GI + 8 * half;

  f32x16 acc[5];
  {
    f32x16 z = {};
#pragma unroll
    for (int c = 0; c < 5; ++c) acc[c] = z;
  }

#pragma unroll 2
  for (int s = 0; s < 48; ++s) {
    const int d0 = s * 16;
    const float4 a0 = *(const float4*)(gi + d0);
    const float4 a1 = *(const float4*)(gi + d0 + 4);
    const float4 b0 = *(const float4*)(gj + d0);
    const float4 b1v = *(const float4*)(gj + d0 + 4);
    float xr[8] = {a0.x * b0.x, a0.y * b0.y, a0.z * b0.z, a0.w * b0.w,
                   a1.x * b1v.x, a1.y * b1v.y, a1.z * b1v.z, a1.w * b1v.w};
    ushort hs[8], ls[8];
#pragma unroll
    for (int j = 0; j < 8; ++j) tsplit(xr[j], hs[j], ls[j]);
    const v8s ah = mk8(hs), al = mk8(ls);
#pragma unroll
    for (int c = 0; c < 5; ++c) {
      const size_t o = ((size_t)(c * 48 + s) * 64 + lane) * 8;
      const v8s bh = *(const v8s*)(WBhi + o);
      const v8s bl = *(const v8s*)(WBlo + o);
      acc[c] = MFMA(ah, bh, acc[c]);
      acc[c] = MFMA(al, bh, acc[c]);
      acc[c] = MFMA(ah, bl, acc[c]);
    }
  }

  // epilogue: + pre_i + pre_j + phi + b1, relu, split to bf16 hi/lo, store
#pragma unroll
  for (int q = 0; q < 16; ++q) {
    const int rr = (q & 3) + 8 * (q >> 2) + 4 * half;
    const int pI = __shfl(iA, rr);
    const int pJ = __shfl(jA, rr);
    const int rd = __shfl(rdL, rr), rg = __shfl(rgL, rr), rs = __shfl(rsL, rr);
    const float* preI = pre + (size_t)pI * 320;
    const float* preJ = pre + (size_t)pJ * 320 + 160;
    const size_t prow = (size_t)(p0 + rr) * 160;
#pragma unroll
    for (int c = 0; c < 5; ++c) {
      const int col = c * 32 + lcol;
      float v = acc[c][q] + b1p[col] + preI[col] + preJ[col]
              + phiW[rd * HPAD + col] + phiW[rg * HPAD + col] + phiW[rs * HPAD + col];
      v = fmaxf(v, 0.f);
      ushort hh, ll; tsplit(v, hh, ll);
      h1hi[prow + col] = hh;
      h1lo[prow + col] = ll;
    }
  }
}

// ---------------- score3: score = relu(h1@W2+b2)@W3 + b3, 1 wave/block -------
// D[h2][pair]: A = packed W2 (rows h2), B = h1 rows per-lane (col = pair).
__global__ __launch_bounds__(64, 3) void score3_kernel(
    const ushort* __restrict__ h1hi, const ushort* __restrict__ h1lo,
    const ushort* __restrict__ W2Bhi, const ushort* __restrict__ W2Blo,
    const float2* __restrict__ b2w3, const float* __restrict__ b3,
    float* __restrict__ sOut, int P) {
  const int lane = threadIdx.x;
  const int lcol = lane & 31, half = lane >> 5;
  const int p0 = blockIdx.x * 32;

  const ushort* hh = h1hi + (size_t)(p0 + lcol) * 160 + 8 * half;
  const ushort* hl = h1lo + (size_t)(p0 + lcol) * 160 + 8 * half;

  f32x16 acc[5];
  {
    f32x16 z = {};
#pragma unroll
    for (int r = 0; r < 5; ++r) acc[r] = z;
  }

#pragma unroll 2
  for (int s = 0; s < 10; ++s) {
    const v8s bh = *(const v8s*)(hh + s * 16);
    const v8s bl = *(const v8s*)(hl + s * 16);
#pragma unroll
    for (int r = 0; r < 5; ++r) {
      const size_t o = ((size_t)(r * 10 + s) * 64 + lane) * 8;
      const v8s ah = *(const v8s*)(W2Bhi + o);
      const v8s al = *(const v8s*)(W2Blo + o);
      acc[r] = MFMA(ah, bh, acc[r]);
      acc[r] = MFMA(al, bh, acc[r]);
      acc[r] = MFMA(ah, bl, acc[r]);
    }
  }

  float part = 0.f;
#pragma unroll
  for (int r = 0; r < 5; ++r) {
#pragma unroll
    for (int q = 0; q < 16; ++q) {
      const int h2 = r * 32 + (q & 3) + 8 * (q >> 2) + 4 * half;
      const float2 bw = b2w3[h2];
      part += fmaxf(acc[r][q] + bw.x, 0.f) * bw.y;
    }
  }
  part += __shfl_xor(part, 32);
  if (lane < 32) sOut[p0 + lane] = part + b3[0];
}

// ---------------- mid: segment softmax -> weighted -> gated g update ----------
__global__ void mid_kernel(const float* __restrict__ g, const float* __restrict__ s1,
                           const int* __restrict__ segs, const int* __restrict__ aI,
                           const float* __restrict__ Wf, const float* __restrict__ bf,
                           float* __restrict__ g2) {
  const int m = blockIdx.x;
  const int t = threadIdx.x;  // 256
  const int st = segs[m], en = segs[m + 1], n = en - st;
  if (n == 0) {
    for (int d = t; d < GI; d += 256) g2[m * GI + d] = g[m * GI + d];
    return;
  }
  __shared__ float red[256];
  float mx = -INFINITY;
  for (int p = st + t; p < en; p += 256) mx = fmaxf(mx, s1[p]);
  red[t] = mx; __syncthreads();
  for (int s = 128; s > 0; s >>= 1) { if (t < s) red[t] = fmaxf(red[t], red[t + s]); __syncthreads(); }
  mx = red[0]; __syncthreads();
  float sm = 0.f;
  for (int p = st + t; p < en; p += 256) sm += expf(s1[p] - mx);
  red[t] = sm; __syncthreads();
  for (int s = 128; s > 0; s >>= 1) { if (t < s) red[t] += red[t + s]; __syncthreads(); }
  const float denom = red[0]; __syncthreads();
  float wv[3] = {0.f, 0.f, 0.f};
  for (int p = st; p < en; ++p) {
    float e = expf(s1[p] - mx);
    const float* gj = g + (size_t)aI[p] * GI;
#pragma unroll
    for (int u = 0; u < 3; ++u) wv[u] += e * gj[t + u * 256];
  }
#pragma unroll
  for (int u = 0; u < 3; ++u) wv[u] /= denom;
  float part = 0.f;
#pragma unroll
  for (int u = 0; u < 3; ++u) {
    int d = t + u * 256;
    part += g[m * GI + d] * Wf[d] + wv[u] * Wf[GI + d];
  }
  red[t] = part; __syncthreads();
  for (int s = 128; s > 0; s >>= 1) { if (t < s) red[t] += red[t + s]; __syncthreads(); }
  const float f = 1.f / (1.f + expf(-(red[0] + bf[0])));
#pragma unroll
  for (int u = 0; u < 3; ++u) {
    int d = t + u * 256;
    g2[m * GI + d] = f * (float)m + (1.f - f) * wv[u];
  }
}

// ---------------- coref_scores[p] = ms[i] + ms[j] + s2[p] ---------------------
__global__ void coref_kernel(const float* __restrict__ ms, const float* __restrict__ s2,
                             const int* __restrict__ mI, const int* __restrict__ aI,
                             float* __restrict__ out, int P) {
  int p = blockIdx.x * 256 + threadIdx.x;
  if (p >= P) return;
  out[p] = ms[mI[p]] + ms[aI[p]] + s2[p];
}

// ---------------- final segment softmax with epsilon --------------------------
__global__ void final_kernel(const float* __restrict__ c, const int* __restrict__ segs,
                             float* __restrict__ pairP, float* __restrict__ epsP) {
  const int m = blockIdx.x;
  const int t = threadIdx.x;  // 256
  const int st = segs[m], en = segs[m + 1], n = en - st;
  __shared__ float red[256];
  float mx = -INFINITY;
  for (int p = st + t; p < en; p += 256) mx = fmaxf(mx, c[p]);
  red[t] = mx; __syncthreads();
  for (int s = 128; s > 0; s >>= 1) { if (t < s) red[t] = fmaxf(red[t], red[t + s]); __syncthreads(); }
  mx = red[0]; __syncthreads();
  const float m2 = (n > 0) ? fmaxf(mx, 0.f) : 0.f;
  float sm = 0.f;
  for (int p = st + t; p < en; p += 256) sm += expf(c[p] - m2);
  red[t] = sm; __syncthreads();
  for (int s = 128; s > 0; s >>= 1) { if (t < s) red[t] += red[t + s]; __syncthreads(); }
  const float denom = red[0] + expf(-m2);
  for (int p = st + t; p < en; p += 256) pairP[p] = expf(c[p] - m2) / denom;
  if (t == 0) epsP[m] = expf(-m2) / denom;
}

extern "C" void kernel_launch(void* const* d_in, const int* in_sizes, int n_in,
                              void* d_out, int out_size, void* d_ws, size_t ws_size,
                              hipStream_t stream) {
  const float* g_i  = (const float*)d_in[0];
  const float* ms   = (const float*)d_in[1];
  const int*   mI   = (const int*)d_in[2];
  const int*   aI   = (const int*)d_in[3];
  const int*   db   = (const int*)d_in[4];
  const int*   ge   = (const int*)d_in[5];
  const int*   sp   = (const int*)d_in[6];
  const float* de   = (const float*)d_in[7];
  const float* gemb = (const float*)d_in[8];
  const float* semb = (const float*)d_in[9];
  const float* W1   = (const float*)d_in[10];
  const float* b1   = (const float*)d_in[11];
  const float* W2   = (const float*)d_in[12];
  const float* b2   = (const float*)d_in[13];
  const float* W3   = (const float*)d_in[14];
  const float* b3   = (const float*)d_in[15];
  const float* Wf   = (const float*)d_in[16];
  const float* bf   = (const float*)d_in[17];

  const int S = in_sizes[0] / GI;
  const int P = in_sizes[2];
  float* out = (float*)d_out;                 // [coref P | pairP P | epsP S]

  char* ws = (char*)d_ws;
  size_t off = 0;
  auto take = [&](size_t bytes) -> char* {
    char* p = ws + off;
    off = (off + bytes + 15) & ~(size_t)15;
    return p;
  };
  int*    segs  = (int*)   take((size_t)(S + 1) * 4);
  float*  phiW  = (float*) take((size_t)21 * HPAD * 4);
  float*  pre   = (float*) take((size_t)S * 320 * 4);
  float*  g2    = (float*) take((size_t)S * GI * 4);
  float*  s1    = (float*) take((size_t)P * 4);
  float*  s2    = (float*) take((size_t)P * 4);
  ushort* WThi  = (ushort*)take((size_t)480 * GI * 2);
  ushort* WTlo  = (ushort*)take((size_t)480 * GI * 2);
  ushort* WBhi  = (ushort*)take((size_t)5 * 48 * 512 * 2);
  ushort* WBlo  = (ushort*)take((size_t)5 * 48 * 512 * 2);
  ushort* W2Bhi = (ushort*)take((size_t)5 * 10 * 512 * 2);
  ushort* W2Blo = (ushort*)take((size_t)5 * 10 * 512 * 2);
  float*  b1p   = (float*) take((size_t)HPAD * 4);
  float2* b2w3  = (float2*)take((size_t)HPAD * 8);
  ushort* h1hi  = (ushort*)take((size_t)P * 160 * 2);
  ushort* h1lo  = (ushort*)take((size_t)P * 160 * 2);

  const int gridSeg = (S + 1 + 255) / 256;
  const int gridPhi = (21 * HPAD + 255) / 256;
  const int padTot  = 480 * GI + 5 * 48 * 512 + 5 * 10 * 512 + 2 * HPAD;
  const int gridPad = (padTot + 255) / 256;
  const dim3 gridPre((S + 63) / 64, 2);
  const int gridH   = P / 32;          // P % 32 == 0
  const int gridCor = (P + 255) / 256;

  seg_kernel<<<gridSeg, 256, 0, stream>>>(mI, segs, P, S);
  phi_kernel<<<gridPhi, 256, 0, stream>>>(de, gemb, semb, W1, phiW);
  pad2_kernel<<<gridPad, 256, 0, stream>>>(W1, W2, b1, b2, W3, WThi, WTlo,
                                           WBhi, WBlo, W2Bhi, W2Blo, b1p, b2w3);

  // iteration 1 (g = g_i)
  pre2_kernel<<<gridPre, 320, 0, stream>>>(g_i, WThi, WTlo, pre, S);
  h1a_kernel<<<gridH, 64, 0, stream>>>(g_i, pre, phiW, WBhi, WBlo, b1p,
                                       mI, aI, db, ge, sp, h1hi, h1lo, P);
  score3_kernel<<<gridH, 64, 0, stream>>>(h1hi, h1lo, W2Bhi, W2Blo, b2w3, b3, s1, P);
  mid_kernel<<<S, 256, 0, stream>>>(g_i, s1, segs, aI, Wf, bf, g2);

  // iteration 2 (g = g2)
  pre2_kernel<<<gridPre, 320, 0, stream>>>(g2, WThi, WTlo, pre, S);
  h1a_kernel<<<gridH, 64, 0, stream>>>(g2, pre, phiW, WBhi, WBlo, b1p,
                                       mI, aI, db, ge, sp, h1hi, h1lo, P);
  score3_kernel<<<gridH, 64, 0, stream>>>(h1hi, h1lo, W2Bhi, W2Blo, b2w3, b3, s2, P);

  // outputs
  coref_kernel<<<gridCor, 256, 0, stream>>>(ms, s2, mI, aI, out, P);
  final_kernel<<<S, 256, 0, stream>>>(out, segs, out + P, out + 2 * (size_t)P);
}